// Round 10
// baseline (6035.640 us; speedup 1.0000x reference)
//
#include <hip/hip_runtime.h>
#include <hip/hip_bf16.h>

#define N_NODES 20000
#define N_EDGES 320000
#define T_STEPS 64
#define F_IN    16
#define HGd     128
#define HTd     256
#define INVN    (1.0f/20000.0f)
#define NTILES   625            // 20000/32  (sage2 tiles)
#define S1_TILES 313            // ceil(20000/64)
#define QSCALE   64.0f
#define INVQ     (1.0f/64.0f)

typedef __attribute__((ext_vector_type(8))) short short8;
typedef __attribute__((ext_vector_type(4))) float f32x4;
typedef __attribute__((ext_vector_type(2))) float f32x2;
typedef __attribute__((ext_vector_type(2))) _Float16 half2t;

static __device__ __forceinline__ ushort f2bf(float f) {
    __hip_bfloat16 b = __float2bfloat16(f);
    return *reinterpret_cast<ushort*>(&b);
}
static __device__ __forceinline__ half2t u2h(uint u) {
    half2t h; __builtin_memcpy(&h, &u, 4); return h;
}
static __device__ __forceinline__ uint packf16(float a, float b) {
    auto h = __builtin_amdgcn_cvt_pkrtz(a, b);
    uint u; __builtin_memcpy(&u, &h, 4); return u;
}

// ---------------- init ----------------
__global__ void k_zero(int* __restrict__ deg, float* __restrict__ HgP,
                       int* __restrict__ cnt, int* __restrict__ jobc,
                       int* __restrict__ bins) {
    int i = blockIdx.x * blockDim.x + threadIdx.x;
    if (i < N_NODES) deg[i] = 0;
    if (i < T_STEPS * 8 * HGd) HgP[i] = 0.0f;
    if (i < 2) cnt[i] = 0;
    if (i < 1024) jobc[i] = 0;
    if (i < 256) bins[i] = 0;
}

__global__ void k_degree(const int* __restrict__ ei, int* __restrict__ deg) {
    int e = blockIdx.x * blockDim.x + threadIdx.x;
    if (e < N_EDGES) atomicAdd(&deg[ei[N_EDGES + e]], 1);
}

__global__ __launch_bounds__(1024) void k_scan(const int* __restrict__ deg,
        int* __restrict__ rp, int* __restrict__ cursor, float* __restrict__ invd) {
    __shared__ int sh[1024];
    __shared__ int carry_s;
    int tid = threadIdx.x;
    if (tid == 0) { carry_s = 0; rp[0] = 0; }
    __syncthreads();
    for (int base = 0; base < N_NODES; base += 1024) {
        int i = base + tid;
        int v = (i < N_NODES) ? deg[i] : 0;
        sh[tid] = v;
        __syncthreads();
        for (int off = 1; off < 1024; off <<= 1) {
            int t = (tid >= off) ? sh[tid - off] : 0;
            __syncthreads();
            sh[tid] += t;
            __syncthreads();
        }
        int inc = sh[tid] + carry_s;
        if (i < N_NODES) {
            rp[i + 1] = inc;
            cursor[i] = inc - v;
            invd[i] = (v > 0) ? (1.0f / (float)v) : 0.0f;
        }
        __syncthreads();
        if (tid == 1023) carry_s = inc;
        __syncthreads();
    }
}

__global__ void k_fill(const int* __restrict__ ei, int* __restrict__ cursor,
                       int* __restrict__ csr) {
    int e = blockIdx.x * blockDim.x + threadIdx.x;
    if (e < N_EDGES) {
        int d = ei[N_EDGES + e];
        int p = atomicAdd(&cursor[d], 1);
        csr[p] = ei[e];
    }
}

// ---------------- degree-sort permutation + permuted CSR ----------------
__global__ void k_hist(const int* __restrict__ deg, int* __restrict__ bins) {
    int i = blockIdx.x * blockDim.x + threadIdx.x;
    if (i < N_NODES) atomicAdd(&bins[min(deg[i], 255)], 1);
}

__global__ __launch_bounds__(256) void k_binscan(const int* __restrict__ bins,
        int* __restrict__ bincur, int* __restrict__ nodebefore, int* __restrict__ edgebefore) {
    __shared__ int sh[256], she[256];
    int tid = threadIdx.x;
    int b = bins[tid];
    sh[tid] = b;
    she[tid] = b * tid;
    __syncthreads();
    for (int off = 1; off < 256; off <<= 1) {
        int v = (tid >= off) ? sh[tid - off] : 0;
        int ve = (tid >= off) ? she[tid - off] : 0;
        __syncthreads();
        sh[tid] += v; she[tid] += ve;
        __syncthreads();
    }
    bincur[tid] = sh[tid] - b;
    nodebefore[tid] = sh[tid] - b;
    edgebefore[tid] = she[tid] - b * tid;
}

__global__ void k_perm(const int* __restrict__ deg, int* __restrict__ bincur,
                       const int* __restrict__ nodebefore, const int* __restrict__ edgebefore,
                       const float* __restrict__ invd,
                       int* __restrict__ perm, int* __restrict__ pos,
                       int* __restrict__ rp2, float* __restrict__ invd2) {
    int i = blockIdx.x * blockDim.x + threadIdx.x;
    if (i < N_NODES) {
        int d = min(deg[i], 255);
        int p = atomicAdd(&bincur[d], 1);
        int rank = p - nodebefore[d];
        perm[p] = i;
        pos[i] = p;
        rp2[p] = edgebefore[d] + rank * d;
        invd2[p] = invd[i];
        if (i == 0) rp2[N_NODES] = N_EDGES;
    }
}

__global__ void k_csr2(const int* __restrict__ rp, const int* __restrict__ pos,
                       const int* __restrict__ rp2, const int* __restrict__ csr,
                       int* __restrict__ csr2) {
    int i = blockIdx.x * blockDim.x + threadIdx.x;
    if (i < N_NODES) {
        int s = rp[i], e = rp[i + 1];
        int o = rp2[pos[i]];
        for (int k = s; k < e; ++k) csr2[o + (k - s)] = csr[k];
    }
}

// ---------------- weight prep ----------------
__global__ void k_prepw(const float* __restrict__ W1l, const float* __restrict__ W1r,
                        const float* __restrict__ W2l, const float* __restrict__ W2r,
                        const float* __restrict__ W_ih, const float* __restrict__ W_hh,
                        float* __restrict__ Wc1, ushort* __restrict__ WT2,
                        float* __restrict__ WihT, uint* __restrict__ W_hhq) {
    int i = blockIdx.x * blockDim.x + threadIdx.x;
    const int n1 = 32 * 128, n2 = 128 * 256, n3 = 128 * 768, n4 = 128 * 768;
    if (i < n1) {
        int k = i >> 7, o = i & 127;
        Wc1[i] = (k < 16) ? W1l[o * 16 + k] : W1r[o * 16 + (k - 16)];
    } else if (i < n1 + n2) {
        int j = i - n1; int o = j >> 8, k = j & 255;
        float v = (k < 128) ? W2l[o * 128 + k] : W2r[o * 128 + (k - 128)];
        WT2[j] = f2bf(v);
    } else if (i < n1 + n2 + n3) {
        int j = i - n1 - n2; int k = j / 768, g = j % 768;
        WihT[j] = W_ih[g * 128 + k];
    } else if (i < n1 + n2 + n3 + n4) {
        int j = i - n1 - n2 - n3; int dw = j / 768, row = j % 768;
        float a = W_hh[(size_t)row * HTd + 2 * dw];
        float b = W_hh[(size_t)row * HTd + 2 * dw + 1];
        W_hhq[j] = packf16(a, b);
    }
}

// ---------------- SAGE layer 1 (mega-dispatch, pipelined gather) ----------------
__global__ __launch_bounds__(256, 4) void k_sage1(
        const float* __restrict__ x_seq, const int* __restrict__ rp2,
        const int* __restrict__ csr2, const float* __restrict__ invd2,
        const float* __restrict__ Wc1, const float* __restrict__ b1l,
        const int* __restrict__ perm, uchar1* __restrict__ h1q_,
        int* __restrict__ jobc, int t0, int C) {
    __shared__ float u[64][32];
    __shared__ float w[32][128];
    __shared__ int pnode[64];
    __shared__ int job_s;
    int tid = threadIdx.x;
    const int xcd = blockIdx.x & 7;
    const int cmin = (C < 8) ? C : 8;
    const int ci = xcd % cmin;
    const int reps = (C >= 8) ? (C >> 3) : 1;
    int* ctr = jobc + ci;
    const int njobs = reps * S1_TILES;

    for (int i = tid; i < 32 * 128; i += 256) ((float*)w)[i] = Wc1[i];

    for (;;) {
        if (tid == 0) job_s = atomicAdd(ctr, 1);
        __syncthreads();
        int job = job_s;
        if (job >= njobs) break;
        int rep = job / S1_TILES;
        int tile = job - rep * S1_TILES;
        int tl = ci + (rep << 3);
        const float* xt = x_seq + (size_t)(t0 + tl) * N_NODES * F_IN;
        char* h1q = (char*)h1q_ + (size_t)tl * N_NODES * HGd;
        int nbase = tile * 64;
        if (tid < 64) pnode[tid] = (nbase + tid < N_NODES) ? perm[nbase + tid] : -1;
        __syncthreads();

        { // aggregation: 4 threads/node, idx-prefetch pipeline, unroll-4
            int n = tid >> 2, q = tid & 3;
            int node = pnode[n];
            float4 acc = make_float4(0, 0, 0, 0);
            float4 root = make_float4(0, 0, 0, 0);
            if (node >= 0) {
                int sl = rp2[nbase + n], el = rp2[nbase + n + 1];
                if (el > sl) {
                    int idx[4];
#pragma unroll
                    for (int uu = 0; uu < 4; ++uu) idx[uu] = csr2[min(sl + uu, el - 1)];
                    for (int j = sl; j < el; j += 4) {
                        float4 v[4];
#pragma unroll
                        for (int uu = 0; uu < 4; ++uu)
                            v[uu] = *reinterpret_cast<const float4*>(xt + (size_t)idx[uu] * F_IN + q * 4);
                        int jn = j + 4;
#pragma unroll
                        for (int uu = 0; uu < 4; ++uu) idx[uu] = csr2[min(jn + uu, el - 1)];
#pragma unroll
                        for (int uu = 0; uu < 4; ++uu) {
                            float m = (j + uu < el) ? 1.0f : 0.0f;
                            acc.x += v[uu].x * m; acc.y += v[uu].y * m;
                            acc.z += v[uu].z * m; acc.w += v[uu].w * m;
                        }
                    }
                }
                float id = invd2[nbase + n];
                acc.x *= id; acc.y *= id; acc.z *= id; acc.w *= id;
                root = *reinterpret_cast<const float4*>(xt + node * F_IN + q * 4);
            }
            *reinterpret_cast<float4*>(&u[n][q * 4]) = acc;
            *reinterpret_cast<float4*>(&u[n][16 + q * 4]) = root;
        }
        __syncthreads();

        // GEMM [64 x 32] @ [32 x 128]; thread tile 8 nodes x 4 outs
        int og = tid & 31, ng = tid >> 5;
        int o = og * 4;
        float acc[8][4];
#pragma unroll
        for (int j = 0; j < 8; ++j)
#pragma unroll
            for (int c = 0; c < 4; ++c) acc[j][c] = 0.0f;

#pragma unroll
        for (int k = 0; k < 32; k += 4) {
            float4 w0 = *reinterpret_cast<const float4*>(&w[k + 0][o]);
            float4 w1 = *reinterpret_cast<const float4*>(&w[k + 1][o]);
            float4 w2 = *reinterpret_cast<const float4*>(&w[k + 2][o]);
            float4 w3 = *reinterpret_cast<const float4*>(&w[k + 3][o]);
#pragma unroll
            for (int j = 0; j < 8; ++j) {
                float4 uv = *reinterpret_cast<const float4*>(&u[ng * 8 + j][k]);
                acc[j][0] += uv.x * w0.x + uv.y * w1.x + uv.z * w2.x + uv.w * w3.x;
                acc[j][1] += uv.x * w0.y + uv.y * w1.y + uv.z * w2.y + uv.w * w3.y;
                acc[j][2] += uv.x * w0.z + uv.y * w1.z + uv.z * w2.z + uv.w * w3.z;
                acc[j][3] += uv.x * w0.w + uv.y * w1.w + uv.z * w2.w + uv.w * w3.w;
            }
        }

        float4 bv = *reinterpret_cast<const float4*>(b1l + o);
#pragma unroll
        for (int j = 0; j < 8; ++j) {
            int node = pnode[ng * 8 + j];
            if (node >= 0) {
                float rx = fmaxf(acc[j][0] + bv.x, 0.0f) * QSCALE;
                float ry = fmaxf(acc[j][1] + bv.y, 0.0f) * QSCALE;
                float rz = fmaxf(acc[j][2] + bv.z, 0.0f) * QSCALE;
                float rw = fmaxf(acc[j][3] + bv.w, 0.0f) * QSCALE;
                int q8 = __builtin_amdgcn_cvt_pk_fp8_f32(rx, ry, 0, false);
                q8 = __builtin_amdgcn_cvt_pk_fp8_f32(rz, rw, q8, true);
                *reinterpret_cast<int*>(h1q + (size_t)node * HGd + o) = q8;
            }
        }
    }
}

// ---------------- SAGE layer 2 (bf16 MFMA, fp8, mega-dispatch, pipelined) ----------------
__global__ __launch_bounds__(256) void k_sage2(
        const uchar1* __restrict__ h1q_,
        const int* __restrict__ rp2, const int* __restrict__ csr2,
        const float* __restrict__ invd2,
        const ushort* __restrict__ WT2, const float* __restrict__ b2l,
        const int* __restrict__ perm, float* __restrict__ HgP,
        int* __restrict__ jobc, int t0, int C) {
    __shared__ uint4 usm4[32 * 512 / 16];   // 16 KB
    __shared__ int pnode[32];
    __shared__ int job_s;
    char* ub = (char*)usm4;
    int tid = threadIdx.x;
    int l = tid & 63, w = tid >> 6;
    int lane15 = l & 15, g4 = l >> 4;
    const int xcd = blockIdx.x & 7;
    const int cmin = (C < 8) ? C : 8;
    const int ci = xcd % cmin;
    const int reps = (C >= 8) ? (C >> 3) : 1;
    int* ctr = jobc + ci;
    const int njobs = reps * NTILES;

    // B-fragment preload: wave w owns cols [w*32, w*32+32)
    short8 bfr[2][8];
    float bb[2];
#pragma unroll
    for (int ct = 0; ct < 2; ++ct) {
        int n = w * 32 + ct * 16 + lane15;
        const ushort* bp = WT2 + n * 256 + g4 * 8;
#pragma unroll
        for (int ks = 0; ks < 8; ++ks)
            bfr[ct][ks] = *reinterpret_cast<const short8*>(bp + ks * 32);
        bb[ct] = b2l[n];
    }

    for (;;) {
        if (tid == 0) job_s = atomicAdd(ctr, 1);
        __syncthreads();
        int job = job_s;
        if (job >= njobs) break;
        int rep = job / NTILES;
        int tile = job - rep * NTILES;
        int tl = ci + ((reps - 1 - rep) << 3);   // reverse: read freshest slice first
        int t = t0 + tl;
        const char* h1q = (const char*)h1q_ + (size_t)tl * N_NODES * HGd;
        int nbase = tile * 32;
        if (tid < 32) pnode[tid] = perm[nbase + tid];
        __syncthreads();

        // root rows (fp8 -> bf16*INVQ): 32 nodes x 8 segs of 16 fp8
        {
            int nl = tid >> 3, seg = tid & 7;
            uint4 v = *reinterpret_cast<const uint4*>(h1q + (size_t)pnode[nl] * HGd + seg * 16);
            uint bw[8];
#pragma unroll
            for (int d = 0; d < 4; ++d) {
                uint vd = d == 0 ? v.x : d == 1 ? v.y : d == 2 ? v.z : v.w;
                f32x2 plo = __builtin_amdgcn_cvt_pk_f32_fp8((int)vd, false);
                f32x2 phi = __builtin_amdgcn_cvt_pk_f32_fp8((int)vd, true);
                bw[2 * d]     = (uint)f2bf(plo.x * INVQ) | ((uint)f2bf(plo.y * INVQ) << 16);
                bw[2 * d + 1] = (uint)f2bf(phi.x * INVQ) | ((uint)f2bf(phi.y * INVQ) << 16);
            }
            int base = nl * 512 + 256 + seg * 32;
            int swz = (nl & 7) << 4;
            *reinterpret_cast<uint4*>(ub + (base ^ swz)) =
                make_uint4(bw[0], bw[1], bw[2], bw[3]);
            *reinterpret_cast<uint4*>(ub + ((base + 16) ^ swz)) =
                make_uint4(bw[4], bw[5], bw[6], bw[7]);
        }

        // gather (fp8): wave w -> 8 nodes, 2 passes of 4; idx-prefetch unroll-8
#pragma unroll
        for (int g = 0; g < 2; ++g) {
            int nl = w * 8 + g * 4 + g4;
            int sl = rp2[nbase + nl], el = rp2[nbase + nl + 1];
            float af[8] = {0, 0, 0, 0, 0, 0, 0, 0};
            if (el > sl) {
                int idx[8];
#pragma unroll
                for (int uu = 0; uu < 8; ++uu) idx[uu] = csr2[min(sl + uu, el - 1)];
                for (int j = sl; j < el; j += 8) {
                    uint2 vv[8];
#pragma unroll
                    for (int uu = 0; uu < 8; ++uu)
                        vv[uu] = *reinterpret_cast<const uint2*>(h1q + (size_t)idx[uu] * HGd + lane15 * 8);
                    int jn = j + 8;
#pragma unroll
                    for (int uu = 0; uu < 8; ++uu) idx[uu] = csr2[min(jn + uu, el - 1)];
#pragma unroll
                    for (int uu = 0; uu < 8; ++uu) {
                        uint vx = (j + uu < el) ? vv[uu].x : 0u;   // fp8 0x00 == 0.0
                        uint vy = (j + uu < el) ? vv[uu].y : 0u;
                        f32x2 p0 = __builtin_amdgcn_cvt_pk_f32_fp8((int)vx, false);
                        f32x2 p1 = __builtin_amdgcn_cvt_pk_f32_fp8((int)vx, true);
                        f32x2 p2 = __builtin_amdgcn_cvt_pk_f32_fp8((int)vy, false);
                        f32x2 p3 = __builtin_amdgcn_cvt_pk_f32_fp8((int)vy, true);
                        af[0] += p0.x; af[1] += p0.y; af[2] += p1.x; af[3] += p1.y;
                        af[4] += p2.x; af[5] += p2.y; af[6] += p3.x; af[7] += p3.y;
                    }
                }
            }
            float id = invd2[nbase + nl] * INVQ;
            uint4 pk;
            pk.x = (uint)f2bf(af[0] * id) | ((uint)f2bf(af[1] * id) << 16);
            pk.y = (uint)f2bf(af[2] * id) | ((uint)f2bf(af[3] * id) << 16);
            pk.z = (uint)f2bf(af[4] * id) | ((uint)f2bf(af[5] * id) << 16);
            pk.w = (uint)f2bf(af[6] * id) | ((uint)f2bf(af[7] * id) << 16);
            *reinterpret_cast<uint4*>(ub + ((nl * 512 + lane15 * 16) ^ ((nl & 7) << 4))) = pk;
        }
        __syncthreads();

        // MFMA: [32 x 256] @ WT2^T -> [32 x 128]; wave w cols w*32..+31
        f32x4 acc[2][2];
#pragma unroll
        for (int rt = 0; rt < 2; ++rt)
#pragma unroll
            for (int ct = 0; ct < 2; ++ct) acc[rt][ct] = (f32x4)(0.0f);

#pragma unroll
        for (int ks = 0; ks < 8; ++ks) {
#pragma unroll
            for (int rt = 0; rt < 2; ++rt) {
                int row = rt * 16 + lane15;
                int byt = (row * 512 + (ks * 32 + g4 * 8) * 2) ^ ((row & 7) << 4);
                short8 af = *reinterpret_cast<const short8*>(ub + byt);
                acc[rt][0] = __builtin_amdgcn_mfma_f32_16x16x32_bf16(af, bfr[0][ks], acc[rt][0], 0, 0, 0);
                acc[rt][1] = __builtin_amdgcn_mfma_f32_16x16x32_bf16(af, bfr[1][ks], acc[rt][1], 0, 0, 0);
            }
        }

        // bias + relu + column sums over 32 nodes -> atomic flush per tile
#pragma unroll
        for (int ct = 0; ct < 2; ++ct) {
            float sum = 0.f;
#pragma unroll
            for (int rt = 0; rt < 2; ++rt)
#pragma unroll
                for (int j = 0; j < 4; ++j)
                    sum += fmaxf(acc[rt][ct][j] + bb[ct], 0.f);
            sum += __shfl_xor(sum, 16);
            sum += __shfl_xor(sum, 32);
            if (g4 == 0) {
                int n = w * 32 + ct * 16 + lane15;
                atomicAdd(&HgP[(t * 8 + (job & 7)) * HGd + n], sum);
            }
        }
    }
}

// ---------------- GRU input gates (folds 8-way Hg partials) ----------------
__global__ __launch_bounds__(768) void k_gi(const float* __restrict__ HgP,
        const float* __restrict__ WihT, const float* __restrict__ b_ih,
        float* __restrict__ gi_all) {
    __shared__ float x[HGd];
    int t = blockIdx.x, g = threadIdx.x;
    if (g < HGd) {
        float s = 0.f;
#pragma unroll
        for (int p = 0; p < 8; ++p) s += HgP[(t * 8 + p) * HGd + g];
        x[g] = s * INVN;
    }
    __syncthreads();
    float a = b_ih[g];
    for (int k = 0; k < HGd; ++k) a += WihT[k * 768 + g] * x[k];
    gi_all[t * 768 + g] = a;
}

// ---------------- single-block GRU + head (f16 dot2, W in VGPRs) ----------------
__global__ __launch_bounds__(768, 3) void k_gru1b(const float* __restrict__ gi_all,
        const uint* __restrict__ W_hhq, const float* __restrict__ b_hh,
        const float* __restrict__ Wh1, const float* __restrict__ bh1,
        const float* __restrict__ Wh2, const float* __restrict__ bh2,
        float* __restrict__ out) {
    int tid = threadIdx.x;               // = row 0..767
    uint wv[128];
#pragma unroll
    for (int i = 0; i < 128; ++i) wv[i] = W_hhq[i * 768 + tid];
    float bh = b_hh[tid];

    __shared__ float hs[HTd];
    __shared__ uint h2s[HTd / 2];
    __shared__ float gh[3 * HTd];
    if (tid < HTd) hs[tid] = 0.0f;
    if (tid < HTd / 2) h2s[tid] = 0u;
    __syncthreads();

    for (int t = 0; t < T_STEPS; ++t) {
        float s = bh;
#pragma unroll
        for (int i = 0; i < 128; i += 4) {
            uint4 hh = *reinterpret_cast<const uint4*>(&h2s[i]);
            s = __builtin_amdgcn_fdot2(u2h(wv[i + 0]), u2h(hh.x), s, false);
            s = __builtin_amdgcn_fdot2(u2h(wv[i + 1]), u2h(hh.y), s, false);
            s = __builtin_amdgcn_fdot2(u2h(wv[i + 2]), u2h(hh.z), s, false);
            s = __builtin_amdgcn_fdot2(u2h(wv[i + 3]), u2h(hh.w), s, false);
        }
        gh[tid] = s;
        __syncthreads();
        if (tid < HTd) {
            float gir = gi_all[t * 768 + tid];
            float giz = gi_all[t * 768 + HTd + tid];
            float gin = gi_all[t * 768 + 2 * HTd + tid];
            float r = 1.0f / (1.0f + expf(-(gir + gh[tid])));
            float z = 1.0f / (1.0f + expf(-(giz + gh[HTd + tid])));
            float n = tanhf(gin + r * gh[2 * HTd + tid]);
            hs[tid] = (1.0f - z) * n + z * hs[tid];
        }
        __syncthreads();
        if (tid < HTd / 2)
            h2s[tid] = packf16(hs[2 * tid], hs[2 * tid + 1]);
        __syncthreads();
    }

    __shared__ float act[64];
    if (tid < 64) {
        float a = bh1[tid];
        const float* wr = Wh1 + tid * HTd;
        for (int k = 0; k < HTd; k += 4) {
            float4 wv4 = *reinterpret_cast<const float4*>(wr + k);
            a += wv4.x * hs[k] + wv4.y * hs[k + 1] + wv4.z * hs[k + 2] + wv4.w * hs[k + 3];
        }
        act[tid] = fmaxf(a, 0.0f);
    }
    __syncthreads();
    if (tid == 0) {
        float y = bh2[0];
        for (int j = 0; j < 64; ++j) y += Wh2[j] * act[j];
        out[0] = y;
    }
}

// ---------------- launch ----------------
extern "C" void kernel_launch(void* const* d_in, const int* in_sizes, int n_in,
                              void* d_out, int out_size, void* d_ws, size_t ws_size,
                              hipStream_t stream) {
    const float* x_seq = (const float*)d_in[0];
    const int*   ei    = (const int*)d_in[1];
    const float* W1l   = (const float*)d_in[2];
    const float* b1l   = (const float*)d_in[3];
    const float* W1r   = (const float*)d_in[4];
    const float* W2l   = (const float*)d_in[5];
    const float* b2l   = (const float*)d_in[6];
    const float* W2r   = (const float*)d_in[7];
    const float* W_ih  = (const float*)d_in[8];
    const float* W_hh  = (const float*)d_in[9];
    const float* b_ih  = (const float*)d_in[10];
    const float* b_hh  = (const float*)d_in[11];
    const float* Wh1   = (const float*)d_in[12];
    const float* bh1   = (const float*)d_in[13];
    const float* Wh2   = (const float*)d_in[14];
    const float* bh2   = (const float*)d_in[15];
    float* out = (float*)d_out;

    char* ws = (char*)d_ws;
    size_t off = 0;
    auto take = [&](size_t nbytes) -> void* {
        void* p = (void*)(ws + off);
        off += (nbytes + 255) & ~(size_t)255;
        return p;
    };
    int*    deg    = (int*)take(N_NODES * 4);
    int*    rp     = (int*)take((N_NODES + 1) * 4);
    int*    cursor = (int*)take(N_NODES * 4);
    int*    csr    = (int*)take(N_EDGES * 4);
    float*  invd   = (float*)take(N_NODES * 4);
    int*    perm   = (int*)take(N_NODES * 4);
    int*    pos    = (int*)take(N_NODES * 4);
    int*    rp2    = (int*)take((N_NODES + 2) * 4);
    int*    csr2   = (int*)take(N_EDGES * 4);
    float*  invd2  = (float*)take(N_NODES * 4);
    int*    bins   = (int*)take(256 * 4);
    int*    bincur = (int*)take(256 * 4);
    int*    nodeb  = (int*)take(256 * 4);
    int*    edgeb  = (int*)take(256 * 4);
    float*  Wc1    = (float*)take(32 * 128 * 4);
    ushort* WT2    = (ushort*)take(128 * 256 * 2);
    float*  WihT   = (float*)take(128 * 768 * 4);
    uint*   W_hhq  = (uint*)take(128 * 768 * 4);
    float*  HgP    = (float*)take(T_STEPS * 8 * HGd * 4);
    float*  gi_all = (float*)take(T_STEPS * 768 * 4);
    int*    cnt    = (int*)take(256);
    int*    jobc   = (int*)take(1024 * 4);

    const size_t slice_q = ((size_t)N_NODES * HGd + 255) & ~(size_t)255;  // 2.56 MB
    int T_CH = 64;
    while (T_CH > 1 && off + (size_t)T_CH * slice_q > ws_size)
        T_CH >>= 1;
    uchar1* h1q = (uchar1*)take((size_t)T_CH * slice_q);

    k_zero<<<256, 256, 0, stream>>>(deg, HgP, cnt, jobc, bins);
    k_degree<<<(N_EDGES + 255) / 256, 256, 0, stream>>>(ei, deg);
    k_scan<<<1, 1024, 0, stream>>>(deg, rp, cursor, invd);
    k_fill<<<(N_EDGES + 255) / 256, 256, 0, stream>>>(ei, cursor, csr);
    k_hist<<<(N_NODES + 255) / 256, 256, 0, stream>>>(deg, bins);
    k_binscan<<<1, 256, 0, stream>>>(bins, bincur, nodeb, edgeb);
    k_perm<<<(N_NODES + 255) / 256, 256, 0, stream>>>(deg, bincur, nodeb, edgeb, invd,
                                                      perm, pos, rp2, invd2);
    k_csr2<<<(N_NODES + 255) / 256, 256, 0, stream>>>(rp, pos, rp2, csr, csr2);
    {
        int total = 32 * 128 + 128 * 256 + 128 * 768 + 128 * 768;
        k_prepw<<<(total + 255) / 256, 256, 0, stream>>>(W1l, W1r, W2l, W2r, W_ih, W_hh,
                                                         Wc1, WT2, WihT, W_hhq);
    }
    int chunk = 0;
    for (int t0 = 0; t0 < T_STEPS; t0 += T_CH, ++chunk) {
        int C = T_CH;
        k_sage1<<<2048, 256, 0, stream>>>(x_seq, rp2, csr2, invd2, Wc1, b1l, perm, h1q,
                                          jobc + chunk * 16, t0, C);
        k_sage2<<<2048, 256, 0, stream>>>(h1q, rp2, csr2, invd2, WT2, b2l, perm, HgP,
                                          jobc + chunk * 16 + 8, t0, C);
    }
    k_gi<<<T_STEPS, 768, 0, stream>>>(HgP, WihT, b_ih, gi_all);
    k_gru1b<<<1, 768, 0, stream>>>(gi_all, W_hhq, b_hh, Wh1, bh1, Wh2, bh2, out);
}

// Round 11
// 2445.970 us; speedup vs baseline: 2.4676x; 2.4676x over previous
//
#include <hip/hip_runtime.h>
#include <hip/hip_bf16.h>

#define N_NODES 20000
#define N_EDGES 320000
#define T_STEPS 64
#define F_IN    16
#define HGd     128
#define HTd     256
#define INVN    (1.0f/20000.0f)
#define NTILES   625            // 20000/32  (sage2 tiles)
#define S1_TILES 313            // ceil(20000/64)
#define QSCALE   64.0f
#define INVQ     (1.0f/64.0f)

typedef __attribute__((ext_vector_type(8))) short short8;
typedef __attribute__((ext_vector_type(4))) float f32x4;
typedef __attribute__((ext_vector_type(2))) float f32x2;
typedef __attribute__((ext_vector_type(2))) _Float16 half2t;

static __device__ __forceinline__ ushort f2bf(float f) {
    __hip_bfloat16 b = __float2bfloat16(f);
    return *reinterpret_cast<ushort*>(&b);
}
static __device__ __forceinline__ half2t u2h(uint u) {
    half2t h; __builtin_memcpy(&h, &u, 4); return h;
}
static __device__ __forceinline__ uint packf16(float a, float b) {
    auto h = __builtin_amdgcn_cvt_pkrtz(a, b);
    uint u; __builtin_memcpy(&u, &h, 4); return u;
}

// ---------------- init ----------------
__global__ void k_zero(int* __restrict__ deg, float* __restrict__ HgP,
                       int* __restrict__ cnt, int* __restrict__ jobc,
                       int* __restrict__ bins) {
    int i = blockIdx.x * blockDim.x + threadIdx.x;
    if (i < N_NODES) deg[i] = 0;
    if (i < T_STEPS * 8 * HGd) HgP[i] = 0.0f;
    if (i < 2) cnt[i] = 0;
    if (i < 1024) jobc[i] = 0;
    if (i < 256) bins[i] = 0;
}

__global__ void k_degree(const int* __restrict__ ei, int* __restrict__ deg) {
    int e = blockIdx.x * blockDim.x + threadIdx.x;
    if (e < N_EDGES) atomicAdd(&deg[ei[N_EDGES + e]], 1);
}

__global__ __launch_bounds__(1024) void k_scan(const int* __restrict__ deg,
        int* __restrict__ rp, int* __restrict__ cursor, float* __restrict__ invd) {
    __shared__ int sh[1024];
    __shared__ int carry_s;
    int tid = threadIdx.x;
    if (tid == 0) { carry_s = 0; rp[0] = 0; }
    __syncthreads();
    for (int base = 0; base < N_NODES; base += 1024) {
        int i = base + tid;
        int v = (i < N_NODES) ? deg[i] : 0;
        sh[tid] = v;
        __syncthreads();
        for (int off = 1; off < 1024; off <<= 1) {
            int t = (tid >= off) ? sh[tid - off] : 0;
            __syncthreads();
            sh[tid] += t;
            __syncthreads();
        }
        int inc = sh[tid] + carry_s;
        if (i < N_NODES) {
            rp[i + 1] = inc;
            cursor[i] = inc - v;
            invd[i] = (v > 0) ? (1.0f / (float)v) : 0.0f;
        }
        __syncthreads();
        if (tid == 1023) carry_s = inc;
        __syncthreads();
    }
}

__global__ void k_fill(const int* __restrict__ ei, int* __restrict__ cursor,
                       int* __restrict__ csr) {
    int e = blockIdx.x * blockDim.x + threadIdx.x;
    if (e < N_EDGES) {
        int d = ei[N_EDGES + e];
        int p = atomicAdd(&cursor[d], 1);
        csr[p] = ei[e];
    }
}

// ---------------- degree-sort permutation + permuted CSR ----------------
__global__ void k_hist(const int* __restrict__ deg, int* __restrict__ bins) {
    int i = blockIdx.x * blockDim.x + threadIdx.x;
    if (i < N_NODES) atomicAdd(&bins[min(deg[i], 255)], 1);
}

__global__ __launch_bounds__(256) void k_binscan(const int* __restrict__ bins,
        int* __restrict__ bincur, int* __restrict__ nodebefore, int* __restrict__ edgebefore) {
    __shared__ int sh[256], she[256];
    int tid = threadIdx.x;
    int b = bins[tid];
    sh[tid] = b;
    she[tid] = b * tid;
    __syncthreads();
    for (int off = 1; off < 256; off <<= 1) {
        int v = (tid >= off) ? sh[tid - off] : 0;
        int ve = (tid >= off) ? she[tid - off] : 0;
        __syncthreads();
        sh[tid] += v; she[tid] += ve;
        __syncthreads();
    }
    bincur[tid] = sh[tid] - b;
    nodebefore[tid] = sh[tid] - b;
    edgebefore[tid] = she[tid] - b * tid;
}

__global__ void k_perm(const int* __restrict__ deg, int* __restrict__ bincur,
                       const int* __restrict__ nodebefore, const int* __restrict__ edgebefore,
                       const float* __restrict__ invd,
                       int* __restrict__ perm, int* __restrict__ pos,
                       int* __restrict__ rp2, float* __restrict__ invd2) {
    int i = blockIdx.x * blockDim.x + threadIdx.x;
    if (i < N_NODES) {
        int d = min(deg[i], 255);
        int p = atomicAdd(&bincur[d], 1);
        int rank = p - nodebefore[d];
        perm[p] = i;
        pos[i] = p;
        rp2[p] = edgebefore[d] + rank * d;
        invd2[p] = invd[i];
        if (i == 0) rp2[N_NODES] = N_EDGES;
    }
}

__global__ void k_csr2(const int* __restrict__ rp, const int* __restrict__ pos,
                       const int* __restrict__ rp2, const int* __restrict__ csr,
                       int* __restrict__ csr2) {
    int i = blockIdx.x * blockDim.x + threadIdx.x;
    if (i < N_NODES) {
        int s = rp[i], e = rp[i + 1];
        int o = rp2[pos[i]];
        for (int k = s; k < e; ++k) csr2[o + (k - s)] = csr[k];
    }
}

// ---------------- weight prep ----------------
__global__ void k_prepw(const float* __restrict__ W1l, const float* __restrict__ W1r,
                        const float* __restrict__ W2l, const float* __restrict__ W2r,
                        const float* __restrict__ W_ih, const float* __restrict__ W_hh,
                        float* __restrict__ Wc1, ushort* __restrict__ WT2,
                        float* __restrict__ WihT, uint* __restrict__ W_hhq) {
    int i = blockIdx.x * blockDim.x + threadIdx.x;
    const int n1 = 32 * 128, n2 = 128 * 256, n3 = 128 * 768, n4 = 128 * 768;
    if (i < n1) {
        int k = i >> 7, o = i & 127;
        Wc1[i] = (k < 16) ? W1l[o * 16 + k] : W1r[o * 16 + (k - 16)];
    } else if (i < n1 + n2) {
        int j = i - n1; int o = j >> 8, k = j & 255;
        float v = (k < 128) ? W2l[o * 128 + k] : W2r[o * 128 + (k - 128)];
        WT2[j] = f2bf(v);
    } else if (i < n1 + n2 + n3) {
        int j = i - n1 - n2; int k = j / 768, g = j % 768;
        WihT[j] = W_ih[g * 128 + k];
    } else if (i < n1 + n2 + n3 + n4) {
        int j = i - n1 - n2 - n3; int dw = j / 768, row = j % 768;
        float a = W_hh[(size_t)row * HTd + 2 * dw];
        float b = W_hh[(size_t)row * HTd + 2 * dw + 1];
        W_hhq[j] = packf16(a, b);
    }
}

// ---------------- SAGE layer 1 (mega-dispatch; VGPR<=128, no spill) ----------------
__global__ __launch_bounds__(256, 2) void k_sage1(
        const float* __restrict__ x_seq, const int* __restrict__ rp2,
        const int* __restrict__ csr2, const float* __restrict__ invd2,
        const float* __restrict__ Wc1, const float* __restrict__ b1l,
        const int* __restrict__ perm, uchar1* __restrict__ h1q_,
        int* __restrict__ jobc, int t0, int C) {
    __shared__ float u[64][32];
    __shared__ float w[32][128];
    __shared__ int pnode[64];
    __shared__ int job_s;
    int tid = threadIdx.x;
    const int xcd = blockIdx.x & 7;
    const int cmin = (C < 8) ? C : 8;
    const int ci = xcd % cmin;
    const int reps = (C >= 8) ? (C >> 3) : 1;
    int* ctr = jobc + ci;
    const int njobs = reps * S1_TILES;

    for (int i = tid; i < 32 * 128; i += 256) ((float*)w)[i] = Wc1[i];

    for (;;) {
        if (tid == 0) job_s = atomicAdd(ctr, 1);
        __syncthreads();
        int job = job_s;
        if (job >= njobs) break;
        int rep = job / S1_TILES;
        int tile = job - rep * S1_TILES;
        int tl = ci + (rep << 3);
        const float* xt = x_seq + (size_t)(t0 + tl) * N_NODES * F_IN;
        char* h1q = (char*)h1q_ + (size_t)tl * N_NODES * HGd;
        int nbase = tile * 64;
        if (tid < 64) pnode[tid] = (nbase + tid < N_NODES) ? perm[nbase + tid] : -1;
        __syncthreads();

        { // aggregation: 4 threads per node, unroll-4 (round-9 form, low reg pressure)
            int n = tid >> 2, q = tid & 3;
            int node = pnode[n];
            float4 acc = make_float4(0, 0, 0, 0);
            float4 root = make_float4(0, 0, 0, 0);
            if (node >= 0) {
                int s = rp2[nbase + n], e = rp2[nbase + n + 1];
                int j = s;
                for (; j + 4 <= e; j += 4) {
                    int i0 = csr2[j], i1 = csr2[j + 1], i2 = csr2[j + 2], i3 = csr2[j + 3];
                    float4 v0 = *reinterpret_cast<const float4*>(xt + i0 * F_IN + q * 4);
                    float4 v1 = *reinterpret_cast<const float4*>(xt + i1 * F_IN + q * 4);
                    float4 v2 = *reinterpret_cast<const float4*>(xt + i2 * F_IN + q * 4);
                    float4 v3 = *reinterpret_cast<const float4*>(xt + i3 * F_IN + q * 4);
                    acc.x += v0.x + v1.x + v2.x + v3.x;
                    acc.y += v0.y + v1.y + v2.y + v3.y;
                    acc.z += v0.z + v1.z + v2.z + v3.z;
                    acc.w += v0.w + v1.w + v2.w + v3.w;
                }
                for (; j < e; ++j) {
                    int sn = csr2[j];
                    float4 v = *reinterpret_cast<const float4*>(xt + sn * F_IN + q * 4);
                    acc.x += v.x; acc.y += v.y; acc.z += v.z; acc.w += v.w;
                }
                float id = invd2[nbase + n];
                acc.x *= id; acc.y *= id; acc.z *= id; acc.w *= id;
                root = *reinterpret_cast<const float4*>(xt + node * F_IN + q * 4);
            }
            *reinterpret_cast<float4*>(&u[n][q * 4]) = acc;
            *reinterpret_cast<float4*>(&u[n][16 + q * 4]) = root;
        }
        __syncthreads();

        // GEMM [64 x 32] @ [32 x 128]; thread tile 8 nodes x 4 outs
        int og = tid & 31, ng = tid >> 5;
        int o = og * 4;
        float acc[8][4];
#pragma unroll
        for (int j = 0; j < 8; ++j)
#pragma unroll
            for (int c = 0; c < 4; ++c) acc[j][c] = 0.0f;

#pragma unroll
        for (int k = 0; k < 32; k += 4) {
            float4 w0 = *reinterpret_cast<const float4*>(&w[k + 0][o]);
            float4 w1 = *reinterpret_cast<const float4*>(&w[k + 1][o]);
            float4 w2 = *reinterpret_cast<const float4*>(&w[k + 2][o]);
            float4 w3 = *reinterpret_cast<const float4*>(&w[k + 3][o]);
#pragma unroll
            for (int j = 0; j < 8; ++j) {
                float4 uv = *reinterpret_cast<const float4*>(&u[ng * 8 + j][k]);
                acc[j][0] += uv.x * w0.x + uv.y * w1.x + uv.z * w2.x + uv.w * w3.x;
                acc[j][1] += uv.x * w0.y + uv.y * w1.y + uv.z * w2.y + uv.w * w3.y;
                acc[j][2] += uv.x * w0.z + uv.y * w1.z + uv.z * w2.z + uv.w * w3.z;
                acc[j][3] += uv.x * w0.w + uv.y * w1.w + uv.z * w2.w + uv.w * w3.w;
            }
        }

        float4 bv = *reinterpret_cast<const float4*>(b1l + o);
#pragma unroll
        for (int j = 0; j < 8; ++j) {
            int node = pnode[ng * 8 + j];
            if (node >= 0) {
                float rx = fmaxf(acc[j][0] + bv.x, 0.0f) * QSCALE;
                float ry = fmaxf(acc[j][1] + bv.y, 0.0f) * QSCALE;
                float rz = fmaxf(acc[j][2] + bv.z, 0.0f) * QSCALE;
                float rw = fmaxf(acc[j][3] + bv.w, 0.0f) * QSCALE;
                int q8 = __builtin_amdgcn_cvt_pk_fp8_f32(rx, ry, 0, false);
                q8 = __builtin_amdgcn_cvt_pk_fp8_f32(rz, rw, q8, true);
                *reinterpret_cast<int*>(h1q + (size_t)node * HGd + o) = q8;
            }
        }
    }
}

// ---------------- SAGE layer 2 (bf16 MFMA, fp8, mega-dispatch, pipelined) ----------------
__global__ __launch_bounds__(256) void k_sage2(
        const uchar1* __restrict__ h1q_,
        const int* __restrict__ rp2, const int* __restrict__ csr2,
        const float* __restrict__ invd2,
        const ushort* __restrict__ WT2, const float* __restrict__ b2l,
        const int* __restrict__ perm, float* __restrict__ HgP,
        int* __restrict__ jobc, int t0, int C) {
    __shared__ uint4 usm4[32 * 512 / 16];   // 16 KB
    __shared__ int pnode[32];
    __shared__ int job_s;
    char* ub = (char*)usm4;
    int tid = threadIdx.x;
    int l = tid & 63, w = tid >> 6;
    int lane15 = l & 15, g4 = l >> 4;
    const int xcd = blockIdx.x & 7;
    const int cmin = (C < 8) ? C : 8;
    const int ci = xcd % cmin;
    const int reps = (C >= 8) ? (C >> 3) : 1;
    int* ctr = jobc + ci;
    const int njobs = reps * NTILES;

    // B-fragment preload: wave w owns cols [w*32, w*32+32)
    short8 bfr[2][8];
    float bb[2];
#pragma unroll
    for (int ct = 0; ct < 2; ++ct) {
        int n = w * 32 + ct * 16 + lane15;
        const ushort* bp = WT2 + n * 256 + g4 * 8;
#pragma unroll
        for (int ks = 0; ks < 8; ++ks)
            bfr[ct][ks] = *reinterpret_cast<const short8*>(bp + ks * 32);
        bb[ct] = b2l[n];
    }

    for (;;) {
        if (tid == 0) job_s = atomicAdd(ctr, 1);
        __syncthreads();
        int job = job_s;
        if (job >= njobs) break;
        int rep = job / NTILES;
        int tile = job - rep * NTILES;
        int tl = ci + ((reps - 1 - rep) << 3);   // reverse: read freshest slice first
        int t = t0 + tl;
        const char* h1q = (const char*)h1q_ + (size_t)tl * N_NODES * HGd;
        int nbase = tile * 32;
        if (tid < 32) pnode[tid] = perm[nbase + tid];
        __syncthreads();

        // root rows (fp8 -> bf16*INVQ): 32 nodes x 8 segs of 16 fp8
        {
            int nl = tid >> 3, seg = tid & 7;
            uint4 v = *reinterpret_cast<const uint4*>(h1q + (size_t)pnode[nl] * HGd + seg * 16);
            uint bw[8];
#pragma unroll
            for (int d = 0; d < 4; ++d) {
                uint vd = d == 0 ? v.x : d == 1 ? v.y : d == 2 ? v.z : v.w;
                f32x2 plo = __builtin_amdgcn_cvt_pk_f32_fp8((int)vd, false);
                f32x2 phi = __builtin_amdgcn_cvt_pk_f32_fp8((int)vd, true);
                bw[2 * d]     = (uint)f2bf(plo.x * INVQ) | ((uint)f2bf(plo.y * INVQ) << 16);
                bw[2 * d + 1] = (uint)f2bf(phi.x * INVQ) | ((uint)f2bf(phi.y * INVQ) << 16);
            }
            int base = nl * 512 + 256 + seg * 32;
            int swz = (nl & 7) << 4;
            *reinterpret_cast<uint4*>(ub + (base ^ swz)) =
                make_uint4(bw[0], bw[1], bw[2], bw[3]);
            *reinterpret_cast<uint4*>(ub + ((base + 16) ^ swz)) =
                make_uint4(bw[4], bw[5], bw[6], bw[7]);
        }

        // gather (fp8): wave w -> 8 nodes, 2 passes of 4; idx-prefetch unroll-8
#pragma unroll
        for (int g = 0; g < 2; ++g) {
            int nl = w * 8 + g * 4 + g4;
            int sl = rp2[nbase + nl], el = rp2[nbase + nl + 1];
            float af[8] = {0, 0, 0, 0, 0, 0, 0, 0};
            if (el > sl) {
                int idx[8];
#pragma unroll
                for (int uu = 0; uu < 8; ++uu) idx[uu] = csr2[min(sl + uu, el - 1)];
                for (int j = sl; j < el; j += 8) {
                    uint2 vv[8];
#pragma unroll
                    for (int uu = 0; uu < 8; ++uu)
                        vv[uu] = *reinterpret_cast<const uint2*>(h1q + (size_t)idx[uu] * HGd + lane15 * 8);
                    int jn = j + 8;
#pragma unroll
                    for (int uu = 0; uu < 8; ++uu) idx[uu] = csr2[min(jn + uu, el - 1)];
#pragma unroll
                    for (int uu = 0; uu < 8; ++uu) {
                        uint vx = (j + uu < el) ? vv[uu].x : 0u;   // fp8 0x00 == 0.0
                        uint vy = (j + uu < el) ? vv[uu].y : 0u;
                        f32x2 p0 = __builtin_amdgcn_cvt_pk_f32_fp8((int)vx, false);
                        f32x2 p1 = __builtin_amdgcn_cvt_pk_f32_fp8((int)vx, true);
                        f32x2 p2 = __builtin_amdgcn_cvt_pk_f32_fp8((int)vy, false);
                        f32x2 p3 = __builtin_amdgcn_cvt_pk_f32_fp8((int)vy, true);
                        af[0] += p0.x; af[1] += p0.y; af[2] += p1.x; af[3] += p1.y;
                        af[4] += p2.x; af[5] += p2.y; af[6] += p3.x; af[7] += p3.y;
                    }
                }
            }
            float id = invd2[nbase + nl] * INVQ;
            uint4 pk;
            pk.x = (uint)f2bf(af[0] * id) | ((uint)f2bf(af[1] * id) << 16);
            pk.y = (uint)f2bf(af[2] * id) | ((uint)f2bf(af[3] * id) << 16);
            pk.z = (uint)f2bf(af[4] * id) | ((uint)f2bf(af[5] * id) << 16);
            pk.w = (uint)f2bf(af[6] * id) | ((uint)f2bf(af[7] * id) << 16);
            *reinterpret_cast<uint4*>(ub + ((nl * 512 + lane15 * 16) ^ ((nl & 7) << 4))) = pk;
        }
        __syncthreads();

        // MFMA: [32 x 256] @ WT2^T -> [32 x 128]; wave w cols w*32..+31
        f32x4 acc[2][2];
#pragma unroll
        for (int rt = 0; rt < 2; ++rt)
#pragma unroll
            for (int ct = 0; ct < 2; ++ct) acc[rt][ct] = (f32x4)(0.0f);

#pragma unroll
        for (int ks = 0; ks < 8; ++ks) {
#pragma unroll
            for (int rt = 0; rt < 2; ++rt) {
                int row = rt * 16 + lane15;
                int byt = (row * 512 + (ks * 32 + g4 * 8) * 2) ^ ((row & 7) << 4);
                short8 af = *reinterpret_cast<const short8*>(ub + byt);
                acc[rt][0] = __builtin_amdgcn_mfma_f32_16x16x32_bf16(af, bfr[0][ks], acc[rt][0], 0, 0, 0);
                acc[rt][1] = __builtin_amdgcn_mfma_f32_16x16x32_bf16(af, bfr[1][ks], acc[rt][1], 0, 0, 0);
            }
        }

        // bias + relu + column sums over 32 nodes -> atomic flush per tile
#pragma unroll
        for (int ct = 0; ct < 2; ++ct) {
            float sum = 0.f;
#pragma unroll
            for (int rt = 0; rt < 2; ++rt)
#pragma unroll
                for (int j = 0; j < 4; ++j)
                    sum += fmaxf(acc[rt][ct][j] + bb[ct], 0.f);
            sum += __shfl_xor(sum, 16);
            sum += __shfl_xor(sum, 32);
            if (g4 == 0) {
                int n = w * 32 + ct * 16 + lane15;
                atomicAdd(&HgP[(t * 8 + (job & 7)) * HGd + n], sum);
            }
        }
    }
}

// ---------------- GRU input gates (folds 8-way Hg partials) ----------------
__global__ __launch_bounds__(768) void k_gi(const float* __restrict__ HgP,
        const float* __restrict__ WihT, const float* __restrict__ b_ih,
        float* __restrict__ gi_all) {
    __shared__ float x[HGd];
    int t = blockIdx.x, g = threadIdx.x;
    if (g < HGd) {
        float s = 0.f;
#pragma unroll
        for (int p = 0; p < 8; ++p) s += HgP[(t * 8 + p) * HGd + g];
        x[g] = s * INVN;
    }
    __syncthreads();
    float a = b_ih[g];
    for (int k = 0; k < HGd; ++k) a += WihT[k * 768 + g] * x[k];
    gi_all[t * 768 + g] = a;
}

// ---------------- single-block GRU + head (f16 dot2, W in VGPRs) ----------------
__global__ __launch_bounds__(768, 3) void k_gru1b(const float* __restrict__ gi_all,
        const uint* __restrict__ W_hhq, const float* __restrict__ b_hh,
        const float* __restrict__ Wh1, const float* __restrict__ bh1,
        const float* __restrict__ Wh2, const float* __restrict__ bh2,
        float* __restrict__ out) {
    int tid = threadIdx.x;               // = row 0..767
    uint wv[128];
#pragma unroll
    for (int i = 0; i < 128; ++i) wv[i] = W_hhq[i * 768 + tid];
    float bh = b_hh[tid];

    __shared__ float hs[HTd];
    __shared__ uint h2s[HTd / 2];
    __shared__ float gh[3 * HTd];
    if (tid < HTd) hs[tid] = 0.0f;
    if (tid < HTd / 2) h2s[tid] = 0u;
    __syncthreads();

    for (int t = 0; t < T_STEPS; ++t) {
        float s = bh;
#pragma unroll
        for (int i = 0; i < 128; i += 4) {
            uint4 hh = *reinterpret_cast<const uint4*>(&h2s[i]);
            s = __builtin_amdgcn_fdot2(u2h(wv[i + 0]), u2h(hh.x), s, false);
            s = __builtin_amdgcn_fdot2(u2h(wv[i + 1]), u2h(hh.y), s, false);
            s = __builtin_amdgcn_fdot2(u2h(wv[i + 2]), u2h(hh.z), s, false);
            s = __builtin_amdgcn_fdot2(u2h(wv[i + 3]), u2h(hh.w), s, false);
        }
        gh[tid] = s;
        __syncthreads();
        if (tid < HTd) {
            float gir = gi_all[t * 768 + tid];
            float giz = gi_all[t * 768 + HTd + tid];
            float gin = gi_all[t * 768 + 2 * HTd + tid];
            float r = 1.0f / (1.0f + expf(-(gir + gh[tid])));
            float z = 1.0f / (1.0f + expf(-(giz + gh[HTd + tid])));
            float n = tanhf(gin + r * gh[2 * HTd + tid]);
            hs[tid] = (1.0f - z) * n + z * hs[tid];
        }
        __syncthreads();
        if (tid < HTd / 2)
            h2s[tid] = packf16(hs[2 * tid], hs[2 * tid + 1]);
        __syncthreads();
    }

    __shared__ float act[64];
    if (tid < 64) {
        float a = bh1[tid];
        const float* wr = Wh1 + tid * HTd;
        for (int k = 0; k < HTd; k += 4) {
            float4 wv4 = *reinterpret_cast<const float4*>(wr + k);
            a += wv4.x * hs[k] + wv4.y * hs[k + 1] + wv4.z * hs[k + 2] + wv4.w * hs[k + 3];
        }
        act[tid] = fmaxf(a, 0.0f);
    }
    __syncthreads();
    if (tid == 0) {
        float y = bh2[0];
        for (int j = 0; j < 64; ++j) y += Wh2[j] * act[j];
        out[0] = y;
    }
}

// ---------------- launch ----------------
extern "C" void kernel_launch(void* const* d_in, const int* in_sizes, int n_in,
                              void* d_out, int out_size, void* d_ws, size_t ws_size,
                              hipStream_t stream) {
    const float* x_seq = (const float*)d_in[0];
    const int*   ei    = (const int*)d_in[1];
    const float* W1l   = (const float*)d_in[2];
    const float* b1l   = (const float*)d_in[3];
    const float* W1r   = (const float*)d_in[4];
    const float* W2l   = (const float*)d_in[5];
    const float* b2l   = (const float*)d_in[6];
    const float* W2r   = (const float*)d_in[7];
    const float* W_ih  = (const float*)d_in[8];
    const float* W_hh  = (const float*)d_in[9];
    const float* b_ih  = (const float*)d_in[10];
    const float* b_hh  = (const float*)d_in[11];
    const float* Wh1   = (const float*)d_in[12];
    const float* bh1   = (const float*)d_in[13];
    const float* Wh2   = (const float*)d_in[14];
    const float* bh2   = (const float*)d_in[15];
    float* out = (float*)d_out;

    char* ws = (char*)d_ws;
    size_t off = 0;
    auto take = [&](size_t nbytes) -> void* {
        void* p = (void*)(ws + off);
        off += (nbytes + 255) & ~(size_t)255;
        return p;
    };
    int*    deg    = (int*)take(N_NODES * 4);
    int*    rp     = (int*)take((N_NODES + 1) * 4);
    int*    cursor = (int*)take(N_NODES * 4);
    int*    csr    = (int*)take(N_EDGES * 4);
    float*  invd   = (float*)take(N_NODES * 4);
    int*    perm   = (int*)take(N_NODES * 4);
    int*    pos    = (int*)take(N_NODES * 4);
    int*    rp2    = (int*)take((N_NODES + 2) * 4);
    int*    csr2   = (int*)take(N_EDGES * 4);
    float*  invd2  = (float*)take(N_NODES * 4);
    int*    bins   = (int*)take(256 * 4);
    int*    bincur = (int*)take(256 * 4);
    int*    nodeb  = (int*)take(256 * 4);
    int*    edgeb  = (int*)take(256 * 4);
    float*  Wc1    = (float*)take(32 * 128 * 4);
    ushort* WT2    = (ushort*)take(128 * 256 * 2);
    float*  WihT   = (float*)take(128 * 768 * 4);
    uint*   W_hhq  = (uint*)take(128 * 768 * 4);
    float*  HgP    = (float*)take(T_STEPS * 8 * HGd * 4);
    float*  gi_all = (float*)take(T_STEPS * 768 * 4);
    int*    cnt    = (int*)take(256);
    int*    jobc   = (int*)take(1024 * 4);

    const size_t slice_q = ((size_t)N_NODES * HGd + 255) & ~(size_t)255;  // 2.56 MB
    int T_CH = 64;
    while (T_CH > 1 && off + (size_t)T_CH * slice_q > ws_size)
        T_CH >>= 1;
    uchar1* h1q = (uchar1*)take((size_t)T_CH * slice_q);

    k_zero<<<256, 256, 0, stream>>>(deg, HgP, cnt, jobc, bins);
    k_degree<<<(N_EDGES + 255) / 256, 256, 0, stream>>>(ei, deg);
    k_scan<<<1, 1024, 0, stream>>>(deg, rp, cursor, invd);
    k_fill<<<(N_EDGES + 255) / 256, 256, 0, stream>>>(ei, cursor, csr);
    k_hist<<<(N_NODES + 255) / 256, 256, 0, stream>>>(deg, bins);
    k_binscan<<<1, 256, 0, stream>>>(bins, bincur, nodeb, edgeb);
    k_perm<<<(N_NODES + 255) / 256, 256, 0, stream>>>(deg, bincur, nodeb, edgeb, invd,
                                                      perm, pos, rp2, invd2);
    k_csr2<<<(N_NODES + 255) / 256, 256, 0, stream>>>(rp, pos, rp2, csr, csr2);
    {
        int total = 32 * 128 + 128 * 256 + 128 * 768 + 128 * 768;
        k_prepw<<<(total + 255) / 256, 256, 0, stream>>>(W1l, W1r, W2l, W2r, W_ih, W_hh,
                                                         Wc1, WT2, WihT, W_hhq);
    }
    int chunk = 0;
    for (int t0 = 0; t0 < T_STEPS; t0 += T_CH, ++chunk) {
        int C = T_CH;
        k_sage1<<<2048, 256, 0, stream>>>(x_seq, rp2, csr2, invd2, Wc1, b1l, perm, h1q,
                                          jobc + chunk * 16, t0, C);
        k_sage2<<<2048, 256, 0, stream>>>(h1q, rp2, csr2, invd2, WT2, b2l, perm, HgP,
                                          jobc + chunk * 16 + 8, t0, C);
    }
    k_gi<<<T_STEPS, 768, 0, stream>>>(HgP, WihT, b_ih, gi_all);
    k_gru1b<<<1, 768, 0, stream>>>(gi_all, W_hhq, b_hh, Wh1, bh1, Wh2, bh2, out);
}

// Round 12
// 1481.171 us; speedup vs baseline: 4.0749x; 1.6514x over previous
//
#include <hip/hip_runtime.h>
#include <hip/hip_bf16.h>

#define N_NODES 20000
#define N_EDGES 320000
#define T_STEPS 64
#define F_IN    16
#define HGd     128
#define HTd     256
#define INVN    (1.0f/20000.0f)
#define NTILES   625            // 20000/32  (sage2 tiles)
#define S1_TILES 313            // ceil(20000/64)
#define QSCALE   64.0f
#define INVQ     (1.0f/64.0f)
#define QX       32.0f
#define INVQX    (1.0f/32.0f)

typedef __attribute__((ext_vector_type(8))) short short8;
typedef __attribute__((ext_vector_type(4))) float f32x4;
typedef __attribute__((ext_vector_type(2))) float f32x2;
typedef __attribute__((ext_vector_type(2))) _Float16 half2t;

static __device__ __forceinline__ ushort f2bf(float f) {
    __hip_bfloat16 b = __float2bfloat16(f);
    return *reinterpret_cast<ushort*>(&b);
}
static __device__ __forceinline__ half2t u2h(uint u) {
    half2t h; __builtin_memcpy(&h, &u, 4); return h;
}
static __device__ __forceinline__ uint packf16(float a, float b) {
    auto h = __builtin_amdgcn_cvt_pkrtz(a, b);
    uint u; __builtin_memcpy(&u, &h, 4); return u;
}

// ---------------- init ----------------
__global__ void k_zero(int* __restrict__ deg, float* __restrict__ HgP,
                       int* __restrict__ cnt, int* __restrict__ jobc,
                       int* __restrict__ bins) {
    int i = blockIdx.x * blockDim.x + threadIdx.x;
    if (i < N_NODES) deg[i] = 0;
    if (i < T_STEPS * 8 * HGd) HgP[i] = 0.0f;
    if (i < 2) cnt[i] = 0;
    if (i < 1024) jobc[i] = 0;
    if (i < 256) bins[i] = 0;
}

__global__ void k_degree(const int* __restrict__ ei, int* __restrict__ deg) {
    int e = blockIdx.x * blockDim.x + threadIdx.x;
    if (e < N_EDGES) atomicAdd(&deg[ei[N_EDGES + e]], 1);
}

__global__ __launch_bounds__(1024) void k_scan(const int* __restrict__ deg,
        int* __restrict__ rp, int* __restrict__ cursor, float* __restrict__ invd) {
    __shared__ int sh[1024];
    __shared__ int carry_s;
    int tid = threadIdx.x;
    if (tid == 0) { carry_s = 0; rp[0] = 0; }
    __syncthreads();
    for (int base = 0; base < N_NODES; base += 1024) {
        int i = base + tid;
        int v = (i < N_NODES) ? deg[i] : 0;
        sh[tid] = v;
        __syncthreads();
        for (int off = 1; off < 1024; off <<= 1) {
            int t = (tid >= off) ? sh[tid - off] : 0;
            __syncthreads();
            sh[tid] += t;
            __syncthreads();
        }
        int inc = sh[tid] + carry_s;
        if (i < N_NODES) {
            rp[i + 1] = inc;
            cursor[i] = inc - v;
            invd[i] = (v > 0) ? (1.0f / (float)v) : 0.0f;
        }
        __syncthreads();
        if (tid == 1023) carry_s = inc;
        __syncthreads();
    }
}

__global__ void k_fill(const int* __restrict__ ei, int* __restrict__ cursor,
                       int* __restrict__ csr) {
    int e = blockIdx.x * blockDim.x + threadIdx.x;
    if (e < N_EDGES) {
        int d = ei[N_EDGES + e];
        int p = atomicAdd(&cursor[d], 1);
        csr[p] = ei[e];
    }
}

// ---------------- degree-sort permutation + permuted CSR ----------------
__global__ void k_hist(const int* __restrict__ deg, int* __restrict__ bins) {
    int i = blockIdx.x * blockDim.x + threadIdx.x;
    if (i < N_NODES) atomicAdd(&bins[min(deg[i], 255)], 1);
}

__global__ __launch_bounds__(256) void k_binscan(const int* __restrict__ bins,
        int* __restrict__ bincur, int* __restrict__ nodebefore, int* __restrict__ edgebefore) {
    __shared__ int sh[256], she[256];
    int tid = threadIdx.x;
    int b = bins[tid];
    sh[tid] = b;
    she[tid] = b * tid;
    __syncthreads();
    for (int off = 1; off < 256; off <<= 1) {
        int v = (tid >= off) ? sh[tid - off] : 0;
        int ve = (tid >= off) ? she[tid - off] : 0;
        __syncthreads();
        sh[tid] += v; she[tid] += ve;
        __syncthreads();
    }
    bincur[tid] = sh[tid] - b;
    nodebefore[tid] = sh[tid] - b;
    edgebefore[tid] = she[tid] - b * tid;
}

__global__ void k_perm(const int* __restrict__ deg, int* __restrict__ bincur,
                       const int* __restrict__ nodebefore, const int* __restrict__ edgebefore,
                       const float* __restrict__ invd,
                       int* __restrict__ perm, int* __restrict__ pos,
                       int* __restrict__ rp2, float* __restrict__ invd2) {
    int i = blockIdx.x * blockDim.x + threadIdx.x;
    if (i < N_NODES) {
        int d = min(deg[i], 255);
        int p = atomicAdd(&bincur[d], 1);
        int rank = p - nodebefore[d];
        perm[p] = i;
        pos[i] = p;
        rp2[p] = edgebefore[d] + rank * d;
        invd2[p] = invd[i];
        if (i == 0) rp2[N_NODES] = N_EDGES;
    }
}

__global__ void k_csr2(const int* __restrict__ rp, const int* __restrict__ pos,
                       const int* __restrict__ rp2, const int* __restrict__ csr,
                       int* __restrict__ csr2) {
    int i = blockIdx.x * blockDim.x + threadIdx.x;
    if (i < N_NODES) {
        int s = rp[i], e = rp[i + 1];
        int o = rp2[pos[i]];
        for (int k = s; k < e; ++k) csr2[o + (k - s)] = csr[k];
    }
}

// ---------------- x_seq fp32 -> fp8 (x32) ----------------
__global__ void k_qx(const float* __restrict__ xs, int* __restrict__ x8, int n4) {
    int i = blockIdx.x * blockDim.x + threadIdx.x;
    if (i < n4) {
        float4 v = reinterpret_cast<const float4*>(xs)[i];
        int q8 = __builtin_amdgcn_cvt_pk_fp8_f32(v.x * QX, v.y * QX, 0, false);
        q8 = __builtin_amdgcn_cvt_pk_fp8_f32(v.z * QX, v.w * QX, q8, true);
        x8[i] = q8;
    }
}

// ---------------- weight prep ----------------
__global__ void k_prepw(const float* __restrict__ W1l, const float* __restrict__ W1r,
                        const float* __restrict__ W2l, const float* __restrict__ W2r,
                        const float* __restrict__ W_ih, const float* __restrict__ W_hh,
                        float* __restrict__ Wc1, ushort* __restrict__ WT2,
                        float* __restrict__ WihT, uint* __restrict__ W_hhq) {
    int i = blockIdx.x * blockDim.x + threadIdx.x;
    const int n1 = 32 * 128, n2 = 128 * 256, n3 = 128 * 768, n4 = 128 * 768;
    if (i < n1) {
        int k = i >> 7, o = i & 127;
        Wc1[i] = (k < 16) ? W1l[o * 16 + k] : W1r[o * 16 + (k - 16)];
    } else if (i < n1 + n2) {
        int j = i - n1; int o = j >> 8, k = j & 255;
        float v = (k < 128) ? W2l[o * 128 + k] : W2r[o * 128 + (k - 128)];
        WT2[j] = f2bf(v);
    } else if (i < n1 + n2 + n3) {
        int j = i - n1 - n2; int k = j / 768, g = j % 768;
        WihT[j] = W_ih[g * 128 + k];
    } else if (i < n1 + n2 + n3 + n4) {
        int j = i - n1 - n2 - n3; int dw = j / 768, row = j % 768;
        float a = W_hh[(size_t)row * HTd + 2 * dw];
        float b = W_hh[(size_t)row * HTd + 2 * dw + 1];
        W_hhq[j] = packf16(a, b);
    }
}

// ---------------- SAGE layer 1 (mega-dispatch, fp8 x, uncapped regs) ----------------
__global__ __launch_bounds__(256) void k_sage1(
        const char* __restrict__ x8_, const int* __restrict__ rp2,
        const int* __restrict__ csr2, const float* __restrict__ invd2,
        const float* __restrict__ Wc1, const float* __restrict__ b1l,
        const int* __restrict__ perm, uchar1* __restrict__ h1q_,
        int* __restrict__ jobc, int C) {
    __shared__ float u[64][32];
    __shared__ float w[32][128];
    __shared__ int pnode[64];
    __shared__ int job_s;
    int tid = threadIdx.x;
    const int xcd = blockIdx.x & 7;
    const int cmin = (C < 8) ? C : 8;
    const int ci = xcd % cmin;
    const int reps = (C >= 8) ? (C >> 3) : 1;
    int* ctr = jobc + ci;
    const int njobs = reps * S1_TILES;

    for (int i = tid; i < 32 * 128; i += 256) ((float*)w)[i] = Wc1[i];

    for (;;) {
        if (tid == 0) job_s = atomicAdd(ctr, 1);
        __syncthreads();
        int job = job_s;
        if (job >= njobs) break;
        int rep = job / S1_TILES;
        int tile = job - rep * S1_TILES;
        int tl = ci + (rep << 3);
        const char* xq = x8_ + (size_t)tl * N_NODES * F_IN;   // 16 B/row fp8
        char* h1q = (char*)h1q_ + (size_t)tl * N_NODES * HGd;
        int nbase = tile * 64;
        if (tid < 64) pnode[tid] = (nbase + tid < N_NODES) ? perm[nbase + tid] : -1;
        __syncthreads();

        { // aggregation: 4 threads/node, lane q covers fp8 elems [4q,4q+4), unroll-4
            int n = tid >> 2, q = tid & 3;
            int node = pnode[n];
            float4 acc = make_float4(0, 0, 0, 0);
            float4 root = make_float4(0, 0, 0, 0);
            if (node >= 0) {
                int s = rp2[nbase + n], e = rp2[nbase + n + 1];
                int j = s;
                for (; j + 4 <= e; j += 4) {
                    int i0 = csr2[j], i1 = csr2[j + 1], i2 = csr2[j + 2], i3 = csr2[j + 3];
                    uint v0 = *reinterpret_cast<const uint*>(xq + i0 * F_IN + q * 4);
                    uint v1 = *reinterpret_cast<const uint*>(xq + i1 * F_IN + q * 4);
                    uint v2 = *reinterpret_cast<const uint*>(xq + i2 * F_IN + q * 4);
                    uint v3 = *reinterpret_cast<const uint*>(xq + i3 * F_IN + q * 4);
#pragma unroll
                    for (int uu = 0; uu < 4; ++uu) {
                        uint vv = uu == 0 ? v0 : uu == 1 ? v1 : uu == 2 ? v2 : v3;
                        f32x2 lo = __builtin_amdgcn_cvt_pk_f32_fp8((int)vv, false);
                        f32x2 hi = __builtin_amdgcn_cvt_pk_f32_fp8((int)vv, true);
                        acc.x += lo.x; acc.y += lo.y; acc.z += hi.x; acc.w += hi.y;
                    }
                }
                for (; j < e; ++j) {
                    int sn = csr2[j];
                    uint vv = *reinterpret_cast<const uint*>(xq + sn * F_IN + q * 4);
                    f32x2 lo = __builtin_amdgcn_cvt_pk_f32_fp8((int)vv, false);
                    f32x2 hi = __builtin_amdgcn_cvt_pk_f32_fp8((int)vv, true);
                    acc.x += lo.x; acc.y += lo.y; acc.z += hi.x; acc.w += hi.y;
                }
                float id = invd2[nbase + n] * INVQX;
                acc.x *= id; acc.y *= id; acc.z *= id; acc.w *= id;
                uint rv = *reinterpret_cast<const uint*>(xq + node * F_IN + q * 4);
                f32x2 lo = __builtin_amdgcn_cvt_pk_f32_fp8((int)rv, false);
                f32x2 hi = __builtin_amdgcn_cvt_pk_f32_fp8((int)rv, true);
                root = make_float4(lo.x * INVQX, lo.y * INVQX, hi.x * INVQX, hi.y * INVQX);
            }
            *reinterpret_cast<float4*>(&u[n][q * 4]) = acc;
            *reinterpret_cast<float4*>(&u[n][16 + q * 4]) = root;
        }
        __syncthreads();

        // GEMM [64 x 32] @ [32 x 128]; thread tile 8 nodes x 4 outs
        int og = tid & 31, ng = tid >> 5;
        int o = og * 4;
        float acc[8][4];
#pragma unroll
        for (int j = 0; j < 8; ++j)
#pragma unroll
            for (int c = 0; c < 4; ++c) acc[j][c] = 0.0f;

#pragma unroll
        for (int k = 0; k < 32; k += 4) {
            float4 w0 = *reinterpret_cast<const float4*>(&w[k + 0][o]);
            float4 w1 = *reinterpret_cast<const float4*>(&w[k + 1][o]);
            float4 w2 = *reinterpret_cast<const float4*>(&w[k + 2][o]);
            float4 w3 = *reinterpret_cast<const float4*>(&w[k + 3][o]);
#pragma unroll
            for (int j = 0; j < 8; ++j) {
                float4 uv = *reinterpret_cast<const float4*>(&u[ng * 8 + j][k]);
                acc[j][0] += uv.x * w0.x + uv.y * w1.x + uv.z * w2.x + uv.w * w3.x;
                acc[j][1] += uv.x * w0.y + uv.y * w1.y + uv.z * w2.y + uv.w * w3.y;
                acc[j][2] += uv.x * w0.z + uv.y * w1.z + uv.z * w2.z + uv.w * w3.z;
                acc[j][3] += uv.x * w0.w + uv.y * w1.w + uv.z * w2.w + uv.w * w3.w;
            }
        }

        float4 bv = *reinterpret_cast<const float4*>(b1l + o);
#pragma unroll
        for (int j = 0; j < 8; ++j) {
            int node = pnode[ng * 8 + j];
            if (node >= 0) {
                float rx = fmaxf(acc[j][0] + bv.x, 0.0f) * QSCALE;
                float ry = fmaxf(acc[j][1] + bv.y, 0.0f) * QSCALE;
                float rz = fmaxf(acc[j][2] + bv.z, 0.0f) * QSCALE;
                float rw = fmaxf(acc[j][3] + bv.w, 0.0f) * QSCALE;
                int q8 = __builtin_amdgcn_cvt_pk_fp8_f32(rx, ry, 0, false);
                q8 = __builtin_amdgcn_cvt_pk_fp8_f32(rz, rw, q8, true);
                *reinterpret_cast<int*>(h1q + (size_t)node * HGd + o) = q8;
            }
        }
    }
}

// ---------------- SAGE layer 2 (bf16 MFMA, fp8, mega-dispatch, pipelined) ----------------
__global__ __launch_bounds__(256) void k_sage2(
        const uchar1* __restrict__ h1q_,
        const int* __restrict__ rp2, const int* __restrict__ csr2,
        const float* __restrict__ invd2,
        const ushort* __restrict__ WT2, const float* __restrict__ b2l,
        const int* __restrict__ perm, float* __restrict__ HgP,
        int* __restrict__ jobc, int t0, int C) {
    __shared__ uint4 usm4[32 * 512 / 16];   // 16 KB
    __shared__ int pnode[32];
    __shared__ int job_s;
    char* ub = (char*)usm4;
    int tid = threadIdx.x;
    int l = tid & 63, w = tid >> 6;
    int lane15 = l & 15, g4 = l >> 4;
    const int xcd = blockIdx.x & 7;
    const int cmin = (C < 8) ? C : 8;
    const int ci = xcd % cmin;
    const int reps = (C >= 8) ? (C >> 3) : 1;
    int* ctr = jobc + ci;
    const int njobs = reps * NTILES;

    // B-fragment preload: wave w owns cols [w*32, w*32+32)
    short8 bfr[2][8];
    float bb[2];
#pragma unroll
    for (int ct = 0; ct < 2; ++ct) {
        int n = w * 32 + ct * 16 + lane15;
        const ushort* bp = WT2 + n * 256 + g4 * 8;
#pragma unroll
        for (int ks = 0; ks < 8; ++ks)
            bfr[ct][ks] = *reinterpret_cast<const short8*>(bp + ks * 32);
        bb[ct] = b2l[n];
    }

    for (;;) {
        if (tid == 0) job_s = atomicAdd(ctr, 1);
        __syncthreads();
        int job = job_s;
        if (job >= njobs) break;
        int rep = job / NTILES;
        int tile = job - rep * NTILES;
        int tl = ci + ((reps - 1 - rep) << 3);   // reverse: read freshest slice first
        int t = t0 + tl;
        const char* h1q = (const char*)h1q_ + (size_t)tl * N_NODES * HGd;
        int nbase = tile * 32;
        if (tid < 32) pnode[tid] = perm[nbase + tid];
        __syncthreads();

        // root rows (fp8 -> bf16*INVQ): 32 nodes x 8 segs of 16 fp8
        {
            int nl = tid >> 3, seg = tid & 7;
            uint4 v = *reinterpret_cast<const uint4*>(h1q + (size_t)pnode[nl] * HGd + seg * 16);
            uint bw[8];
#pragma unroll
            for (int d = 0; d < 4; ++d) {
                uint vd = d == 0 ? v.x : d == 1 ? v.y : d == 2 ? v.z : v.w;
                f32x2 plo = __builtin_amdgcn_cvt_pk_f32_fp8((int)vd, false);
                f32x2 phi = __builtin_amdgcn_cvt_pk_f32_fp8((int)vd, true);
                bw[2 * d]     = (uint)f2bf(plo.x * INVQ) | ((uint)f2bf(plo.y * INVQ) << 16);
                bw[2 * d + 1] = (uint)f2bf(phi.x * INVQ) | ((uint)f2bf(phi.y * INVQ) << 16);
            }
            int base = nl * 512 + 256 + seg * 32;
            int swz = (nl & 7) << 4;
            *reinterpret_cast<uint4*>(ub + (base ^ swz)) =
                make_uint4(bw[0], bw[1], bw[2], bw[3]);
            *reinterpret_cast<uint4*>(ub + ((base + 16) ^ swz)) =
                make_uint4(bw[4], bw[5], bw[6], bw[7]);
        }

        // gather (fp8): wave w -> 8 nodes, 2 passes of 4; idx-prefetch unroll-8
#pragma unroll
        for (int g = 0; g < 2; ++g) {
            int nl = w * 8 + g * 4 + g4;
            int sl = rp2[nbase + nl], el = rp2[nbase + nl + 1];
            float af[8] = {0, 0, 0, 0, 0, 0, 0, 0};
            if (el > sl) {
                int idx[8];
#pragma unroll
                for (int uu = 0; uu < 8; ++uu) idx[uu] = csr2[min(sl + uu, el - 1)];
                for (int j = sl; j < el; j += 8) {
                    uint2 vv[8];
#pragma unroll
                    for (int uu = 0; uu < 8; ++uu)
                        vv[uu] = *reinterpret_cast<const uint2*>(h1q + (size_t)idx[uu] * HGd + lane15 * 8);
                    int jn = j + 8;
#pragma unroll
                    for (int uu = 0; uu < 8; ++uu) idx[uu] = csr2[min(jn + uu, el - 1)];
#pragma unroll
                    for (int uu = 0; uu < 8; ++uu) {
                        uint vx = (j + uu < el) ? vv[uu].x : 0u;   // fp8 0x00 == 0.0
                        uint vy = (j + uu < el) ? vv[uu].y : 0u;
                        f32x2 p0 = __builtin_amdgcn_cvt_pk_f32_fp8((int)vx, false);
                        f32x2 p1 = __builtin_amdgcn_cvt_pk_f32_fp8((int)vx, true);
                        f32x2 p2 = __builtin_amdgcn_cvt_pk_f32_fp8((int)vy, false);
                        f32x2 p3 = __builtin_amdgcn_cvt_pk_f32_fp8((int)vy, true);
                        af[0] += p0.x; af[1] += p0.y; af[2] += p1.x; af[3] += p1.y;
                        af[4] += p2.x; af[5] += p2.y; af[6] += p3.x; af[7] += p3.y;
                    }
                }
            }
            float id = invd2[nbase + nl] * INVQ;
            uint4 pk;
            pk.x = (uint)f2bf(af[0] * id) | ((uint)f2bf(af[1] * id) << 16);
            pk.y = (uint)f2bf(af[2] * id) | ((uint)f2bf(af[3] * id) << 16);
            pk.z = (uint)f2bf(af[4] * id) | ((uint)f2bf(af[5] * id) << 16);
            pk.w = (uint)f2bf(af[6] * id) | ((uint)f2bf(af[7] * id) << 16);
            *reinterpret_cast<uint4*>(ub + ((nl * 512 + lane15 * 16) ^ ((nl & 7) << 4))) = pk;
        }
        __syncthreads();

        // MFMA: [32 x 256] @ WT2^T -> [32 x 128]; wave w cols w*32..+31
        f32x4 acc[2][2];
#pragma unroll
        for (int rt = 0; rt < 2; ++rt)
#pragma unroll
            for (int ct = 0; ct < 2; ++ct) acc[rt][ct] = (f32x4)(0.0f);

#pragma unroll
        for (int ks = 0; ks < 8; ++ks) {
#pragma unroll
            for (int rt = 0; rt < 2; ++rt) {
                int row = rt * 16 + lane15;
                int byt = (row * 512 + (ks * 32 + g4 * 8) * 2) ^ ((row & 7) << 4);
                short8 af = *reinterpret_cast<const short8*>(ub + byt);
                acc[rt][0] = __builtin_amdgcn_mfma_f32_16x16x32_bf16(af, bfr[0][ks], acc[rt][0], 0, 0, 0);
                acc[rt][1] = __builtin_amdgcn_mfma_f32_16x16x32_bf16(af, bfr[1][ks], acc[rt][1], 0, 0, 0);
            }
        }

        // bias + relu + column sums over 32 nodes -> atomic flush per tile
#pragma unroll
        for (int ct = 0; ct < 2; ++ct) {
            float sum = 0.f;
#pragma unroll
            for (int rt = 0; rt < 2; ++rt)
#pragma unroll
                for (int j = 0; j < 4; ++j)
                    sum += fmaxf(acc[rt][ct][j] + bb[ct], 0.f);
            sum += __shfl_xor(sum, 16);
            sum += __shfl_xor(sum, 32);
            if (g4 == 0) {
                int n = w * 32 + ct * 16 + lane15;
                atomicAdd(&HgP[(t * 8 + (job & 7)) * HGd + n], sum);
            }
        }
    }
}

// ---------------- GRU input gates (folds 8-way Hg partials) ----------------
__global__ __launch_bounds__(768) void k_gi(const float* __restrict__ HgP,
        const float* __restrict__ WihT, const float* __restrict__ b_ih,
        float* __restrict__ gi_all) {
    __shared__ float x[HGd];
    int t = blockIdx.x, g = threadIdx.x;
    if (g < HGd) {
        float s = 0.f;
#pragma unroll
        for (int p = 0; p < 8; ++p) s += HgP[(t * 8 + p) * HGd + g];
        x[g] = s * INVN;
    }
    __syncthreads();
    float a = b_ih[g];
    for (int k = 0; k < HGd; ++k) a += WihT[k * 768 + g] * x[k];
    gi_all[t * 768 + g] = a;
}

// ---------------- single-block GRU + head (f16 dot2, W in VGPRs) ----------------
__global__ __launch_bounds__(768, 3) void k_gru1b(const float* __restrict__ gi_all,
        const uint* __restrict__ W_hhq, const float* __restrict__ b_hh,
        const float* __restrict__ Wh1, const float* __restrict__ bh1,
        const float* __restrict__ Wh2, const float* __restrict__ bh2,
        float* __restrict__ out) {
    int tid = threadIdx.x;               // = row 0..767
    uint wv[128];
#pragma unroll
    for (int i = 0; i < 128; ++i) wv[i] = W_hhq[i * 768 + tid];
    float bh = b_hh[tid];

    __shared__ float hs[HTd];
    __shared__ uint h2s[HTd / 2];
    __shared__ float gh[3 * HTd];
    if (tid < HTd) hs[tid] = 0.0f;
    if (tid < HTd / 2) h2s[tid] = 0u;
    __syncthreads();

    for (int t = 0; t < T_STEPS; ++t) {
        float s = bh;
#pragma unroll
        for (int i = 0; i < 128; i += 4) {
            uint4 hh = *reinterpret_cast<const uint4*>(&h2s[i]);
            s = __builtin_amdgcn_fdot2(u2h(wv[i + 0]), u2h(hh.x), s, false);
            s = __builtin_amdgcn_fdot2(u2h(wv[i + 1]), u2h(hh.y), s, false);
            s = __builtin_amdgcn_fdot2(u2h(wv[i + 2]), u2h(hh.z), s, false);
            s = __builtin_amdgcn_fdot2(u2h(wv[i + 3]), u2h(hh.w), s, false);
        }
        gh[tid] = s;
        __syncthreads();
        if (tid < HTd) {
            float gir = gi_all[t * 768 + tid];
            float giz = gi_all[t * 768 + HTd + tid];
            float gin = gi_all[t * 768 + 2 * HTd + tid];
            float r = 1.0f / (1.0f + expf(-(gir + gh[tid])));
            float z = 1.0f / (1.0f + expf(-(giz + gh[HTd + tid])));
            float n = tanhf(gin + r * gh[2 * HTd + tid]);
            hs[tid] = (1.0f - z) * n + z * hs[tid];
        }
        __syncthreads();
        if (tid < HTd / 2)
            h2s[tid] = packf16(hs[2 * tid], hs[2 * tid + 1]);
        __syncthreads();
    }

    __shared__ float act[64];
    if (tid < 64) {
        float a = bh1[tid];
        const float* wr = Wh1 + tid * HTd;
        for (int k = 0; k < HTd; k += 4) {
            float4 wv4 = *reinterpret_cast<const float4*>(wr + k);
            a += wv4.x * hs[k] + wv4.y * hs[k + 1] + wv4.z * hs[k + 2] + wv4.w * hs[k + 3];
        }
        act[tid] = fmaxf(a, 0.0f);
    }
    __syncthreads();
    if (tid == 0) {
        float y = bh2[0];
        for (int j = 0; j < 64; ++j) y += Wh2[j] * act[j];
        out[0] = y;
    }
}

// ---------------- launch ----------------
extern "C" void kernel_launch(void* const* d_in, const int* in_sizes, int n_in,
                              void* d_out, int out_size, void* d_ws, size_t ws_size,
                              hipStream_t stream) {
    const float* x_seq = (const float*)d_in[0];
    const int*   ei    = (const int*)d_in[1];
    const float* W1l   = (const float*)d_in[2];
    const float* b1l   = (const float*)d_in[3];
    const float* W1r   = (const float*)d_in[4];
    const float* W2l   = (const float*)d_in[5];
    const float* b2l   = (const float*)d_in[6];
    const float* W2r   = (const float*)d_in[7];
    const float* W_ih  = (const float*)d_in[8];
    const float* W_hh  = (const float*)d_in[9];
    const float* b_ih  = (const float*)d_in[10];
    const float* b_hh  = (const float*)d_in[11];
    const float* Wh1   = (const float*)d_in[12];
    const float* bh1   = (const float*)d_in[13];
    const float* Wh2   = (const float*)d_in[14];
    const float* bh2   = (const float*)d_in[15];
    float* out = (float*)d_out;

    char* ws = (char*)d_ws;
    size_t off = 0;
    auto take = [&](size_t nbytes) -> void* {
        void* p = (void*)(ws + off);
        off += (nbytes + 255) & ~(size_t)255;
        return p;
    };
    int*    deg    = (int*)take(N_NODES * 4);
    int*    rp     = (int*)take((N_NODES + 1) * 4);
    int*    cursor = (int*)take(N_NODES * 4);
    int*    csr    = (int*)take(N_EDGES * 4);
    float*  invd   = (float*)take(N_NODES * 4);
    int*    perm   = (int*)take(N_NODES * 4);
    int*    pos    = (int*)take(N_NODES * 4);
    int*    rp2    = (int*)take((N_NODES + 2) * 4);
    int*    csr2   = (int*)take(N_EDGES * 4);
    float*  invd2  = (float*)take(N_NODES * 4);
    int*    bins   = (int*)take(256 * 4);
    int*    bincur = (int*)take(256 * 4);
    int*    nodeb  = (int*)take(256 * 4);
    int*    edgeb  = (int*)take(256 * 4);
    float*  Wc1    = (float*)take(32 * 128 * 4);
    ushort* WT2    = (ushort*)take(128 * 256 * 2);
    float*  WihT   = (float*)take(128 * 768 * 4);
    uint*   W_hhq  = (uint*)take(128 * 768 * 4);
    float*  HgP    = (float*)take(T_STEPS * 8 * HGd * 4);
    float*  gi_all = (float*)take(T_STEPS * 768 * 4);
    int*    cnt    = (int*)take(256);
    int*    jobc   = (int*)take(1024 * 4);

    const size_t slice_q = ((size_t)N_NODES * HGd + 255) & ~(size_t)255;      // 2.56 MB
    const size_t slice_x = ((size_t)N_NODES * F_IN + 255) & ~(size_t)255;     // 320 KB
    int T_CH = 64;
    while (T_CH > 1 && off + (size_t)T_CH * (slice_q + slice_x) > ws_size)
        T_CH >>= 1;
    uchar1* h1q = (uchar1*)take((size_t)T_CH * slice_q);
    char*   x8  = (char*)take((size_t)T_CH * slice_x);

    k_zero<<<256, 256, 0, stream>>>(deg, HgP, cnt, jobc, bins);
    k_degree<<<(N_EDGES + 255) / 256, 256, 0, stream>>>(ei, deg);
    k_scan<<<1, 1024, 0, stream>>>(deg, rp, cursor, invd);
    k_fill<<<(N_EDGES + 255) / 256, 256, 0, stream>>>(ei, cursor, csr);
    k_hist<<<(N_NODES + 255) / 256, 256, 0, stream>>>(deg, bins);
    k_binscan<<<1, 256, 0, stream>>>(bins, bincur, nodeb, edgeb);
    k_perm<<<(N_NODES + 255) / 256, 256, 0, stream>>>(deg, bincur, nodeb, edgeb, invd,
                                                      perm, pos, rp2, invd2);
    k_csr2<<<(N_NODES + 255) / 256, 256, 0, stream>>>(rp, pos, rp2, csr, csr2);
    {
        int total = 32 * 128 + 128 * 256 + 128 * 768 + 128 * 768;
        k_prepw<<<(total + 255) / 256, 256, 0, stream>>>(W1l, W1r, W2l, W2r, W_ih, W_hh,
                                                         Wc1, WT2, WihT, W_hhq);
    }
    int chunk = 0;
    for (int t0 = 0; t0 < T_STEPS; t0 += T_CH, ++chunk) {
        int C = T_CH;
        int n4 = C * N_NODES * F_IN / 4;
        k_qx<<<(n4 + 255) / 256, 256, 0, stream>>>(
            x_seq + (size_t)t0 * N_NODES * F_IN, (int*)x8, n4);
        k_sage1<<<2048, 256, 0, stream>>>(x8, rp2, csr2, invd2, Wc1, b1l, perm, h1q,
                                          jobc + (chunk & 1) * 16, C);
        k_sage2<<<2048, 256, 0, stream>>>(h1q, rp2, csr2, invd2, WT2, b2l, perm, HgP,
                                          jobc + (chunk & 1) * 16 + 8, t0, C);
    }
    k_gi<<<T_STEPS, 768, 0, stream>>>(HgP, WihT, b_ih, gi_all);
    k_gru1b<<<1, 768, 0, stream>>>(gi_all, W_hhq, b_hh, Wh1, bh1, Wh2, bh2, out);
}

// Round 13
// 1058.789 us; speedup vs baseline: 5.7005x; 1.3989x over previous
//
#include <hip/hip_runtime.h>
#include <hip/hip_bf16.h>

#define N_NODES 20000
#define N_EDGES 320000
#define T_STEPS 64
#define F_IN    16
#define HGd     128
#define HTd     256
#define INVN    (1.0f/20000.0f)
#define NTILES   625            // 20000/32  (sage2 tiles)
#define S1T      79             // ceil(20000/256) (sage1 tiles of 256)
#define NG64     313            // ceil(20000/64)
#define QSCALE   64.0f
#define INVQ     (1.0f/64.0f)
#define QX       32.0f
#define INVQX    (1.0f/32.0f)

typedef __attribute__((ext_vector_type(8))) short short8;
typedef __attribute__((ext_vector_type(4))) float f32x4;
typedef __attribute__((ext_vector_type(2))) float f32x2;
typedef __attribute__((ext_vector_type(2))) _Float16 half2t;

static __device__ __forceinline__ ushort f2bf(float f) {
    __hip_bfloat16 b = __float2bfloat16(f);
    return *reinterpret_cast<ushort*>(&b);
}
static __device__ __forceinline__ half2t u2h(uint u) {
    half2t h; __builtin_memcpy(&h, &u, 4); return h;
}
static __device__ __forceinline__ uint packf16(float a, float b) {
    auto h = __builtin_amdgcn_cvt_pkrtz(a, b);
    uint u; __builtin_memcpy(&u, &h, 4); return u;
}

// ---------------- init ----------------
__global__ void k_zero(int* __restrict__ deg, float* __restrict__ HgP,
                       int* __restrict__ cnt, int* __restrict__ jobc,
                       int* __restrict__ bins) {
    int i = blockIdx.x * blockDim.x + threadIdx.x;
    if (i < N_NODES) deg[i] = 0;
    if (i < T_STEPS * 8 * HGd) HgP[i] = 0.0f;
    if (i < 2) cnt[i] = 0;
    if (i < 1024) jobc[i] = 0;
    if (i < 256) bins[i] = 0;
}

__global__ void k_degree(const int* __restrict__ ei, int* __restrict__ deg) {
    int e = blockIdx.x * blockDim.x + threadIdx.x;
    if (e < N_EDGES) atomicAdd(&deg[ei[N_EDGES + e]], 1);
}

__global__ __launch_bounds__(1024) void k_scan(const int* __restrict__ deg,
        int* __restrict__ rp, int* __restrict__ cursor, float* __restrict__ invd) {
    __shared__ int sh[1024];
    __shared__ int carry_s;
    int tid = threadIdx.x;
    if (tid == 0) { carry_s = 0; rp[0] = 0; }
    __syncthreads();
    for (int base = 0; base < N_NODES; base += 1024) {
        int i = base + tid;
        int v = (i < N_NODES) ? deg[i] : 0;
        sh[tid] = v;
        __syncthreads();
        for (int off = 1; off < 1024; off <<= 1) {
            int t = (tid >= off) ? sh[tid - off] : 0;
            __syncthreads();
            sh[tid] += t;
            __syncthreads();
        }
        int inc = sh[tid] + carry_s;
        if (i < N_NODES) {
            rp[i + 1] = inc;
            cursor[i] = inc - v;
            invd[i] = (v > 0) ? (1.0f / (float)v) : 0.0f;
        }
        __syncthreads();
        if (tid == 1023) carry_s = inc;
        __syncthreads();
    }
}

__global__ void k_fill(const int* __restrict__ ei, int* __restrict__ cursor,
                       int* __restrict__ csr) {
    int e = blockIdx.x * blockDim.x + threadIdx.x;
    if (e < N_EDGES) {
        int d = ei[N_EDGES + e];
        int p = atomicAdd(&cursor[d], 1);
        csr[p] = ei[e];
    }
}

// ---------------- degree-sort permutation + permuted CSR ----------------
__global__ void k_hist(const int* __restrict__ deg, int* __restrict__ bins) {
    int i = blockIdx.x * blockDim.x + threadIdx.x;
    if (i < N_NODES) atomicAdd(&bins[min(deg[i], 255)], 1);
}

__global__ __launch_bounds__(256) void k_binscan(const int* __restrict__ bins,
        int* __restrict__ bincur, int* __restrict__ nodebefore, int* __restrict__ edgebefore) {
    __shared__ int sh[256], she[256];
    int tid = threadIdx.x;
    int b = bins[tid];
    sh[tid] = b;
    she[tid] = b * tid;
    __syncthreads();
    for (int off = 1; off < 256; off <<= 1) {
        int v = (tid >= off) ? sh[tid - off] : 0;
        int ve = (tid >= off) ? she[tid - off] : 0;
        __syncthreads();
        sh[tid] += v; she[tid] += ve;
        __syncthreads();
    }
    bincur[tid] = sh[tid] - b;
    nodebefore[tid] = sh[tid] - b;
    edgebefore[tid] = she[tid] - b * tid;
}

__global__ void k_perm(const int* __restrict__ deg, int* __restrict__ bincur,
                       const int* __restrict__ nodebefore, const int* __restrict__ edgebefore,
                       const float* __restrict__ invd,
                       int* __restrict__ perm, int* __restrict__ pos,
                       int* __restrict__ rp2, float* __restrict__ invd2,
                       int* __restrict__ degs2) {
    int i = blockIdx.x * blockDim.x + threadIdx.x;
    if (i < N_NODES) {
        int d = min(deg[i], 255);
        int p = atomicAdd(&bincur[d], 1);
        int rank = p - nodebefore[d];
        perm[p] = i;
        pos[i] = p;
        rp2[p] = edgebefore[d] + rank * d;
        invd2[p] = invd[i];
        degs2[p] = deg[i];
        if (i == 0) rp2[N_NODES] = N_EDGES;
    }
}

__global__ void k_csr2(const int* __restrict__ rp, const int* __restrict__ pos,
                       const int* __restrict__ rp2, const int* __restrict__ csr,
                       int* __restrict__ csr2) {
    int i = blockIdx.x * blockDim.x + threadIdx.x;
    if (i < N_NODES) {
        int s = rp[i], e = rp[i + 1];
        int o = rp2[pos[i]];
        for (int k = s; k < e; ++k) csr2[o + (k - s)] = csr[k];
    }
}

// per-64-group transposed edge-list bases: tb[g+1] = tb[g] + 64*maxdeg(g)
__global__ __launch_bounds__(512) void k_tb(const int* __restrict__ rp2, int* __restrict__ tb) {
    __shared__ int sh[512];
    int t = threadIdx.x;
    int md = 0;
    if (t < NG64 && t * 64 < N_NODES) {
        int last = min((t + 1) * 64, N_NODES) - 1;
        md = rp2[last + 1] - rp2[last];
    }
    sh[t] = 64 * md;
    __syncthreads();
    for (int off = 1; off < 512; off <<= 1) {
        int v = (t >= off) ? sh[t - off] : 0;
        __syncthreads();
        sh[t] += v;
        __syncthreads();
    }
    tb[t + 1] = sh[t];
    if (t == 0) tb[0] = 0;
}

__global__ void k_csr3(const int* __restrict__ rp2, const int* __restrict__ tb,
                       const int* __restrict__ csr2, int* __restrict__ csr3) {
    int p = blockIdx.x * blockDim.x + threadIdx.x;
    if (p < N_NODES) {
        int s = rp2[p], d = rp2[p + 1] - s;
        int base = tb[p >> 6];
        int lane = p & 63;
        for (int j = 0; j < d; ++j) csr3[base + j * 64 + lane] = csr2[s + j];
    }
}

// ---------------- x_seq fp32 -> fp8 (x32) ----------------
__global__ void k_qx(const float* __restrict__ xs, int* __restrict__ x8, int n4) {
    int i = blockIdx.x * blockDim.x + threadIdx.x;
    if (i < n4) {
        float4 v = reinterpret_cast<const float4*>(xs)[i];
        int q8 = __builtin_amdgcn_cvt_pk_fp8_f32(v.x * QX, v.y * QX, 0, false);
        q8 = __builtin_amdgcn_cvt_pk_fp8_f32(v.z * QX, v.w * QX, q8, true);
        x8[i] = q8;
    }
}

// ---------------- weight prep ----------------
// W1T2 [128 o][32 k] bf16 (k<16: W1l, else W1r); WT2 [128][256] bf16; WihT; W_hhq f16
__global__ void k_prepw(const float* __restrict__ W1l, const float* __restrict__ W1r,
                        const float* __restrict__ W2l, const float* __restrict__ W2r,
                        const float* __restrict__ W_ih, const float* __restrict__ W_hh,
                        ushort* __restrict__ W1T2, ushort* __restrict__ WT2,
                        float* __restrict__ WihT, uint* __restrict__ W_hhq) {
    int i = blockIdx.x * blockDim.x + threadIdx.x;
    const int n1 = 128 * 32, n2 = 128 * 256, n3 = 128 * 768, n4 = 128 * 768;
    if (i < n1) {
        int o = i >> 5, k = i & 31;
        float v = (k < 16) ? W1l[o * 16 + k] : W1r[o * 16 + (k - 16)];
        W1T2[i] = f2bf(v);
    } else if (i < n1 + n2) {
        int j = i - n1; int o = j >> 8, k = j & 255;
        float v = (k < 128) ? W2l[o * 128 + k] : W2r[o * 128 + (k - 128)];
        WT2[j] = f2bf(v);
    } else if (i < n1 + n2 + n3) {
        int j = i - n1 - n2; int k = j / 768, g = j % 768;
        WihT[j] = W_ih[g * 128 + k];
    } else if (i < n1 + n2 + n3 + n4) {
        int j = i - n1 - n2 - n3; int dw = j / 768, row = j % 768;
        float a = W_hh[(size_t)row * HTd + 2 * dw];
        float b = W_hh[(size_t)row * HTd + 2 * dw + 1];
        W_hhq[j] = packf16(a, b);
    }
}

// ---------------- SAGE layer 1 (lane-per-node gather + MFMA GEMM) ----------------
__global__ __launch_bounds__(256) void k_sage1(
        const char* __restrict__ x8_, const int* __restrict__ tb,
        const int* __restrict__ csr3, const int* __restrict__ degs2,
        const float* __restrict__ invd2,
        const ushort* __restrict__ W1T2, const float* __restrict__ b1l,
        const int* __restrict__ perm, uchar1* __restrict__ h1q_,
        int* __restrict__ jobc, int C) {
    __shared__ ushort u[256 * 40];   // 256 rows x 32 bf16 (+8 pad) = 20 KB, stride 80 B
    __shared__ int pnode[256];
    __shared__ int job_s;
    int tid = threadIdx.x;
    int l = tid & 63, w = tid >> 6;
    int lane15 = l & 15, g4 = l >> 4;
    const int xcd = blockIdx.x & 7;
    const int cmin = (C < 8) ? C : 8;
    const int ci = xcd % cmin;
    const int reps = (C >= 8) ? (C >> 3) : 1;
    int* ctr = jobc + ci;
    const int njobs = reps * S1T;

    // B-fragments: wave w -> output cols [w*32, w*32+32)
    short8 bfr1[2];
    float bb1[2];
#pragma unroll
    for (int ct = 0; ct < 2; ++ct) {
        int o16 = w * 32 + ct * 16 + lane15;
        bfr1[ct] = *reinterpret_cast<const short8*>(W1T2 + o16 * 32 + g4 * 8);
        bb1[ct] = b1l[o16];
    }

    for (;;) {
        if (tid == 0) job_s = atomicAdd(ctr, 1);
        __syncthreads();                 // job ready; prior MFMA reads of u done
        int job = job_s;
        if (job >= njobs) break;
        int rep = job / S1T;
        int tile = job - rep * S1T;
        int tl = ci + (rep << 3);
        const char* xq = x8_ + (size_t)tl * N_NODES * F_IN;
        char* h1q = (char*)h1q_ + (size_t)tl * N_NODES * HGd;
        int p = tile * 256 + tid;
        int node = (p < N_NODES) ? perm[p] : -1;
        pnode[tid] = node;

        // gather: one lane per node, full 16-fp8 row per edge
        float acc[16];
#pragma unroll
        for (int k = 0; k < 16; ++k) acc[k] = 0.0f;
        float rootv[16];
#pragma unroll
        for (int k = 0; k < 16; ++k) rootv[k] = 0.0f;
        if (node >= 0) {
            int d = degs2[p];
            const int base = tb[p >> 6] + (p & 63);
            for (int j = 0; j < d; ++j) {
                int idx = csr3[base + j * 64];
                uint4 row = *reinterpret_cast<const uint4*>(xq + (size_t)idx * F_IN);
#pragma unroll
                for (int c = 0; c < 4; ++c) {
                    uint vd = c == 0 ? row.x : c == 1 ? row.y : c == 2 ? row.z : row.w;
                    f32x2 lo = __builtin_amdgcn_cvt_pk_f32_fp8((int)vd, false);
                    f32x2 hi = __builtin_amdgcn_cvt_pk_f32_fp8((int)vd, true);
                    acc[4 * c + 0] += lo.x; acc[4 * c + 1] += lo.y;
                    acc[4 * c + 2] += hi.x; acc[4 * c + 3] += hi.y;
                }
            }
            float id = invd2[p] * INVQX;
#pragma unroll
            for (int k = 0; k < 16; ++k) acc[k] *= id;
            uint4 rv = *reinterpret_cast<const uint4*>(xq + (size_t)node * F_IN);
#pragma unroll
            for (int c = 0; c < 4; ++c) {
                uint vd = c == 0 ? rv.x : c == 1 ? rv.y : c == 2 ? rv.z : rv.w;
                f32x2 lo = __builtin_amdgcn_cvt_pk_f32_fp8((int)vd, false);
                f32x2 hi = __builtin_amdgcn_cvt_pk_f32_fp8((int)vd, true);
                rootv[4 * c + 0] = lo.x * INVQX; rootv[4 * c + 1] = lo.y * INVQX;
                rootv[4 * c + 2] = hi.x * INVQX; rootv[4 * c + 3] = hi.y * INVQX;
            }
        }
        // pack row to LDS bf16: [agg(16) | root(16)]
        {
            uint dw[16];
#pragma unroll
            for (int i = 0; i < 8; ++i)
                dw[i] = (uint)f2bf(acc[2 * i]) | ((uint)f2bf(acc[2 * i + 1]) << 16);
#pragma unroll
            for (int i = 0; i < 8; ++i)
                dw[8 + i] = (uint)f2bf(rootv[2 * i]) | ((uint)f2bf(rootv[2 * i + 1]) << 16);
            ushort* ur = u + tid * 40;
#pragma unroll
            for (int c = 0; c < 4; ++c)
                *reinterpret_cast<uint4*>(ur + c * 8) =
                    make_uint4(dw[4 * c], dw[4 * c + 1], dw[4 * c + 2], dw[4 * c + 3]);
        }
        __syncthreads();

        // MFMA GEMM: [256 x 32] @ W1T2^T -> [256 x 128]; wave w cols w*32..+31
#pragma unroll 4
        for (int rt = 0; rt < 16; ++rt) {
            int row = rt * 16 + lane15;
            short8 af = *reinterpret_cast<const short8*>(u + row * 40 + g4 * 8);
            f32x4 a0 = __builtin_amdgcn_mfma_f32_16x16x32_bf16(af, bfr1[0], (f32x4)(0.0f), 0, 0, 0);
            f32x4 a1 = __builtin_amdgcn_mfma_f32_16x16x32_bf16(af, bfr1[1], (f32x4)(0.0f), 0, 0, 0);
#pragma unroll
            for (int j = 0; j < 4; ++j) {
                int nl = rt * 16 + g4 * 4 + j;
                int nd = pnode[nl];
                if (nd >= 0) {
                    float v0 = fmaxf(a0[j] + bb1[0], 0.0f) * QSCALE;
                    float v1 = fmaxf(a1[j] + bb1[1], 0.0f) * QSCALE;
                    int q0 = __builtin_amdgcn_cvt_pk_fp8_f32(v0, v0, 0, false);
                    int q1 = __builtin_amdgcn_cvt_pk_fp8_f32(v1, v1, 0, false);
                    h1q[(size_t)nd * HGd + w * 32 + lane15] = (char)q0;
                    h1q[(size_t)nd * HGd + w * 32 + 16 + lane15] = (char)q1;
                }
            }
        }
    }
}

// ---------------- SAGE layer 2 (bf16 MFMA, fp8, mega-dispatch, pipelined) ----------------
__global__ __launch_bounds__(256) void k_sage2(
        const uchar1* __restrict__ h1q_,
        const int* __restrict__ rp2, const int* __restrict__ csr2,
        const float* __restrict__ invd2,
        const ushort* __restrict__ WT2, const float* __restrict__ b2l,
        const int* __restrict__ perm, float* __restrict__ HgP,
        int* __restrict__ jobc, int t0, int C) {
    __shared__ uint4 usm4[32 * 512 / 16];   // 16 KB
    __shared__ int pnode[32];
    __shared__ int job_s;
    char* ub = (char*)usm4;
    int tid = threadIdx.x;
    int l = tid & 63, w = tid >> 6;
    int lane15 = l & 15, g4 = l >> 4;
    const int xcd = blockIdx.x & 7;
    const int cmin = (C < 8) ? C : 8;
    const int ci = xcd % cmin;
    const int reps = (C >= 8) ? (C >> 3) : 1;
    int* ctr = jobc + ci;
    const int njobs = reps * NTILES;

    short8 bfr[2][8];
    float bb[2];
#pragma unroll
    for (int ct = 0; ct < 2; ++ct) {
        int n = w * 32 + ct * 16 + lane15;
        const ushort* bp = WT2 + n * 256 + g4 * 8;
#pragma unroll
        for (int ks = 0; ks < 8; ++ks)
            bfr[ct][ks] = *reinterpret_cast<const short8*>(bp + ks * 32);
        bb[ct] = b2l[n];
    }

    for (;;) {
        if (tid == 0) job_s = atomicAdd(ctr, 1);
        __syncthreads();
        int job = job_s;
        if (job >= njobs) break;
        int rep = job / NTILES;
        int tile = job - rep * NTILES;
        int tl = ci + ((reps - 1 - rep) << 3);
        int t = t0 + tl;
        const char* h1q = (const char*)h1q_ + (size_t)tl * N_NODES * HGd;
        int nbase = tile * 32;
        if (tid < 32) pnode[tid] = perm[nbase + tid];
        __syncthreads();

        // root rows (fp8 -> bf16*INVQ)
        {
            int nl = tid >> 3, seg = tid & 7;
            uint4 v = *reinterpret_cast<const uint4*>(h1q + (size_t)pnode[nl] * HGd + seg * 16);
            uint bw[8];
#pragma unroll
            for (int d = 0; d < 4; ++d) {
                uint vd = d == 0 ? v.x : d == 1 ? v.y : d == 2 ? v.z : v.w;
                f32x2 plo = __builtin_amdgcn_cvt_pk_f32_fp8((int)vd, false);
                f32x2 phi = __builtin_amdgcn_cvt_pk_f32_fp8((int)vd, true);
                bw[2 * d]     = (uint)f2bf(plo.x * INVQ) | ((uint)f2bf(plo.y * INVQ) << 16);
                bw[2 * d + 1] = (uint)f2bf(phi.x * INVQ) | ((uint)f2bf(phi.y * INVQ) << 16);
            }
            int base = nl * 512 + 256 + seg * 32;
            int swz = (nl & 7) << 4;
            *reinterpret_cast<uint4*>(ub + (base ^ swz)) =
                make_uint4(bw[0], bw[1], bw[2], bw[3]);
            *reinterpret_cast<uint4*>(ub + ((base + 16) ^ swz)) =
                make_uint4(bw[4], bw[5], bw[6], bw[7]);
        }

        // gather (fp8): wave w -> 8 nodes, 2 passes of 4; idx-prefetch unroll-8
#pragma unroll
        for (int g = 0; g < 2; ++g) {
            int nl = w * 8 + g * 4 + g4;
            int sl = rp2[nbase + nl], el = rp2[nbase + nl + 1];
            float af[8] = {0, 0, 0, 0, 0, 0, 0, 0};
            if (el > sl) {
                int idx[8];
#pragma unroll
                for (int uu = 0; uu < 8; ++uu) idx[uu] = csr2[min(sl + uu, el - 1)];
                for (int j = sl; j < el; j += 8) {
                    uint2 vv[8];
#pragma unroll
                    for (int uu = 0; uu < 8; ++uu)
                        vv[uu] = *reinterpret_cast<const uint2*>(h1q + (size_t)idx[uu] * HGd + lane15 * 8);
                    int jn = j + 8;
#pragma unroll
                    for (int uu = 0; uu < 8; ++uu) idx[uu] = csr2[min(jn + uu, el - 1)];
#pragma unroll
                    for (int uu = 0; uu < 8; ++uu) {
                        uint vx = (j + uu < el) ? vv[uu].x : 0u;
                        uint vy = (j + uu < el) ? vv[uu].y : 0u;
                        f32x2 p0 = __builtin_amdgcn_cvt_pk_f32_fp8((int)vx, false);
                        f32x2 p1 = __builtin_amdgcn_cvt_pk_f32_fp8((int)vx, true);
                        f32x2 p2 = __builtin_amdgcn_cvt_pk_f32_fp8((int)vy, false);
                        f32x2 p3 = __builtin_amdgcn_cvt_pk_f32_fp8((int)vy, true);
                        af[0] += p0.x; af[1] += p0.y; af[2] += p1.x; af[3] += p1.y;
                        af[4] += p2.x; af[5] += p2.y; af[6] += p3.x; af[7] += p3.y;
                    }
                }
            }
            float id = invd2[nbase + nl] * INVQ;
            uint4 pk;
            pk.x = (uint)f2bf(af[0] * id) | ((uint)f2bf(af[1] * id) << 16);
            pk.y = (uint)f2bf(af[2] * id) | ((uint)f2bf(af[3] * id) << 16);
            pk.z = (uint)f2bf(af[4] * id) | ((uint)f2bf(af[5] * id) << 16);
            pk.w = (uint)f2bf(af[6] * id) | ((uint)f2bf(af[7] * id) << 16);
            *reinterpret_cast<uint4*>(ub + ((nl * 512 + lane15 * 16) ^ ((nl & 7) << 4))) = pk;
        }
        __syncthreads();

        // MFMA: [32 x 256] @ WT2^T -> [32 x 128]
        f32x4 acc[2][2];
#pragma unroll
        for (int rt = 0; rt < 2; ++rt)
#pragma unroll
            for (int ct = 0; ct < 2; ++ct) acc[rt][ct] = (f32x4)(0.0f);

#pragma unroll
        for (int ks = 0; ks < 8; ++ks) {
#pragma unroll
            for (int rt = 0; rt < 2; ++rt) {
                int row = rt * 16 + lane15;
                int byt = (row * 512 + (ks * 32 + g4 * 8) * 2) ^ ((row & 7) << 4);
                short8 af = *reinterpret_cast<const short8*>(ub + byt);
                acc[rt][0] = __builtin_amdgcn_mfma_f32_16x16x32_bf16(af, bfr[0][ks], acc[rt][0], 0, 0, 0);
                acc[rt][1] = __builtin_amdgcn_mfma_f32_16x16x32_bf16(af, bfr[1][ks], acc[rt][1], 0, 0, 0);
            }
        }

#pragma unroll
        for (int ct = 0; ct < 2; ++ct) {
            float sum = 0.f;
#pragma unroll
            for (int rt = 0; rt < 2; ++rt)
#pragma unroll
                for (int j = 0; j < 4; ++j)
                    sum += fmaxf(acc[rt][ct][j] + bb[ct], 0.f);
            sum += __shfl_xor(sum, 16);
            sum += __shfl_xor(sum, 32);
            if (g4 == 0) {
                int n = w * 32 + ct * 16 + lane15;
                atomicAdd(&HgP[(t * 8 + (job & 7)) * HGd + n], sum);
            }
        }
    }
}

// ---------------- GRU input gates (folds 8-way Hg partials) ----------------
__global__ __launch_bounds__(768) void k_gi(const float* __restrict__ HgP,
        const float* __restrict__ WihT, const float* __restrict__ b_ih,
        float* __restrict__ gi_all) {
    __shared__ float x[HGd];
    int t = blockIdx.x, g = threadIdx.x;
    if (g < HGd) {
        float s = 0.f;
#pragma unroll
        for (int p = 0; p < 8; ++p) s += HgP[(t * 8 + p) * HGd + g];
        x[g] = s * INVN;
    }
    __syncthreads();
    float a = b_ih[g];
    for (int k = 0; k < HGd; ++k) a += WihT[k * 768 + g] * x[k];
    gi_all[t * 768 + g] = a;
}

// ---------------- single-block GRU + head (f16 dot2, W in VGPRs) ----------------
__global__ __launch_bounds__(768, 3) void k_gru1b(const float* __restrict__ gi_all,
        const uint* __restrict__ W_hhq, const float* __restrict__ b_hh,
        const float* __restrict__ Wh1, const float* __restrict__ bh1,
        const float* __restrict__ Wh2, const float* __restrict__ bh2,
        float* __restrict__ out) {
    int tid = threadIdx.x;
    uint wv[128];
#pragma unroll
    for (int i = 0; i < 128; ++i) wv[i] = W_hhq[i * 768 + tid];
    float bh = b_hh[tid];

    __shared__ float hs[HTd];
    __shared__ uint h2s[HTd / 2];
    __shared__ float gh[3 * HTd];
    if (tid < HTd) hs[tid] = 0.0f;
    if (tid < HTd / 2) h2s[tid] = 0u;
    __syncthreads();

    for (int t = 0; t < T_STEPS; ++t) {
        float s = bh;
#pragma unroll
        for (int i = 0; i < 128; i += 4) {
            uint4 hh = *reinterpret_cast<const uint4*>(&h2s[i]);
            s = __builtin_amdgcn_fdot2(u2h(wv[i + 0]), u2h(hh.x), s, false);
            s = __builtin_amdgcn_fdot2(u2h(wv[i + 1]), u2h(hh.y), s, false);
            s = __builtin_amdgcn_fdot2(u2h(wv[i + 2]), u2h(hh.z), s, false);
            s = __builtin_amdgcn_fdot2(u2h(wv[i + 3]), u2h(hh.w), s, false);
        }
        gh[tid] = s;
        __syncthreads();
        if (tid < HTd) {
            float gir = gi_all[t * 768 + tid];
            float giz = gi_all[t * 768 + HTd + tid];
            float gin = gi_all[t * 768 + 2 * HTd + tid];
            float r = 1.0f / (1.0f + expf(-(gir + gh[tid])));
            float z = 1.0f / (1.0f + expf(-(giz + gh[HTd + tid])));
            float n = tanhf(gin + r * gh[2 * HTd + tid]);
            hs[tid] = (1.0f - z) * n + z * hs[tid];
        }
        __syncthreads();
        if (tid < HTd / 2)
            h2s[tid] = packf16(hs[2 * tid], hs[2 * tid + 1]);
        __syncthreads();
    }

    __shared__ float act[64];
    if (tid < 64) {
        float a = bh1[tid];
        const float* wr = Wh1 + tid * HTd;
        for (int k = 0; k < HTd; k += 4) {
            float4 wv4 = *reinterpret_cast<const float4*>(wr + k);
            a += wv4.x * hs[k] + wv4.y * hs[k + 1] + wv4.z * hs[k + 2] + wv4.w * hs[k + 3];
        }
        act[tid] = fmaxf(a, 0.0f);
    }
    __syncthreads();
    if (tid == 0) {
        float y = bh2[0];
        for (int j = 0; j < 64; ++j) y += Wh2[j] * act[j];
        out[0] = y;
    }
}

// ---------------- launch ----------------
extern "C" void kernel_launch(void* const* d_in, const int* in_sizes, int n_in,
                              void* d_out, int out_size, void* d_ws, size_t ws_size,
                              hipStream_t stream) {
    const float* x_seq = (const float*)d_in[0];
    const int*   ei    = (const int*)d_in[1];
    const float* W1l   = (const float*)d_in[2];
    const float* b1l   = (const float*)d_in[3];
    const float* W1r   = (const float*)d_in[4];
    const float* W2l   = (const float*)d_in[5];
    const float* b2l   = (const float*)d_in[6];
    const float* W2r   = (const float*)d_in[7];
    const float* W_ih  = (const float*)d_in[8];
    const float* W_hh  = (const float*)d_in[9];
    const float* b_ih  = (const float*)d_in[10];
    const float* b_hh  = (const float*)d_in[11];
    const float* Wh1   = (const float*)d_in[12];
    const float* bh1   = (const float*)d_in[13];
    const float* Wh2   = (const float*)d_in[14];
    const float* bh2   = (const float*)d_in[15];
    float* out = (float*)d_out;

    char* ws = (char*)d_ws;
    size_t off = 0;
    auto take = [&](size_t nbytes) -> void* {
        void* p = (void*)(ws + off);
        off += (nbytes + 255) & ~(size_t)255;
        return p;
    };
    int*    deg    = (int*)take(N_NODES * 4);
    int*    rp     = (int*)take((N_NODES + 1) * 4);
    int*    cursor = (int*)take(N_NODES * 4);
    int*    csr    = (int*)take(N_EDGES * 4);
    float*  invd   = (float*)take(N_NODES * 4);
    int*    perm   = (int*)take(N_NODES * 4);
    int*    pos    = (int*)take(N_NODES * 4);
    int*    rp2    = (int*)take((N_NODES + 2) * 4);
    int*    csr2   = (int*)take(N_EDGES * 4);
    float*  invd2  = (float*)take(N_NODES * 4);
    int*    degs2  = (int*)take(N_NODES * 4);
    int*    tb     = (int*)take(520 * 4);
    int*    csr3   = (int*)take(360000 * 4);
    int*    bins   = (int*)take(256 * 4);
    int*    bincur = (int*)take(256 * 4);
    int*    nodeb  = (int*)take(256 * 4);
    int*    edgeb  = (int*)take(256 * 4);
    ushort* W1T2   = (ushort*)take(128 * 32 * 2);
    ushort* WT2    = (ushort*)take(128 * 256 * 2);
    float*  WihT   = (float*)take(128 * 768 * 4);
    uint*   W_hhq  = (uint*)take(128 * 768 * 4);
    float*  HgP    = (float*)take(T_STEPS * 8 * HGd * 4);
    float*  gi_all = (float*)take(T_STEPS * 768 * 4);
    int*    cnt    = (int*)take(256);
    int*    jobc   = (int*)take(1024 * 4);

    const size_t slice_q = ((size_t)N_NODES * HGd + 255) & ~(size_t)255;
    const size_t slice_x = ((size_t)N_NODES * F_IN + 255) & ~(size_t)255;
    int T_CH = 64;
    while (T_CH > 1 && off + (size_t)T_CH * (slice_q + slice_x) > ws_size)
        T_CH >>= 1;
    uchar1* h1q = (uchar1*)take((size_t)T_CH * slice_q);
    char*   x8  = (char*)take((size_t)T_CH * slice_x);

    k_zero<<<256, 256, 0, stream>>>(deg, HgP, cnt, jobc, bins);
    k_degree<<<(N_EDGES + 255) / 256, 256, 0, stream>>>(ei, deg);
    k_scan<<<1, 1024, 0, stream>>>(deg, rp, cursor, invd);
    k_fill<<<(N_EDGES + 255) / 256, 256, 0, stream>>>(ei, cursor, csr);
    k_hist<<<(N_NODES + 255) / 256, 256, 0, stream>>>(deg, bins);
    k_binscan<<<1, 256, 0, stream>>>(bins, bincur, nodeb, edgeb);
    k_perm<<<(N_NODES + 255) / 256, 256, 0, stream>>>(deg, bincur, nodeb, edgeb, invd,
                                                      perm, pos, rp2, invd2, degs2);
    k_csr2<<<(N_NODES + 255) / 256, 256, 0, stream>>>(rp, pos, rp2, csr, csr2);
    k_tb<<<1, 512, 0, stream>>>(rp2, tb);
    k_csr3<<<(N_NODES + 255) / 256, 256, 0, stream>>>(rp2, tb, csr2, csr3);
    {
        int total = 128 * 32 + 128 * 256 + 128 * 768 + 128 * 768;
        k_prepw<<<(total + 255) / 256, 256, 0, stream>>>(W1l, W1r, W2l, W2r, W_ih, W_hh,
                                                         W1T2, WT2, WihT, W_hhq);
    }
    int chunk = 0;
    for (int t0 = 0; t0 < T_STEPS; t0 += T_CH, ++chunk) {
        int C = T_CH;
        int n4 = C * N_NODES * F_IN / 4;
        k_qx<<<(n4 + 255) / 256, 256, 0, stream>>>(
            x_seq + (size_t)t0 * N_NODES * F_IN, (int*)x8, n4);
        k_sage1<<<2048, 256, 0, stream>>>(x8, tb, csr3, degs2, invd2, W1T2, b1l, perm,
                                          h1q, jobc + (chunk & 1) * 16, C);
        k_sage2<<<2048, 256, 0, stream>>>(h1q, rp2, csr2, invd2, WT2, b2l, perm, HgP,
                                          jobc + (chunk & 1) * 16 + 8, t0, C);
    }
    k_gi<<<T_STEPS, 768, 0, stream>>>(HgP, WihT, b_ih, gi_all);
    k_gru1b<<<1, 768, 0, stream>>>(gi_all, W_hhq, b_hh, Wh1, bh1, Wh2, bh2, out);
}